// Round 15
// baseline (367.848 us; speedup 1.0000x reference)
//
#include <hip/hip_runtime.h>
#include <hip/hip_bf16.h>
#include <math.h>

#define B_  2
#define T_  2048
#define D_  1024
#define H_  16
#define DK_ 64
#define FF_ 4096
#define BT_ (B_*T_)

typedef __attribute__((ext_vector_type(8))) short bf16x8;
typedef __attribute__((ext_vector_type(4))) float f32x4;

__device__ __forceinline__ ushort f2bf(float f) {
    __hip_bfloat16 h = __float2bfloat16(f);
    return *reinterpret_cast<ushort*>(&h);
}
__device__ __forceinline__ float bf2f(ushort u) {
    __hip_bfloat16 h;
    *reinterpret_cast<ushort*>(&h) = u;
    return __bfloat162float(h);
}
__device__ __forceinline__ uint pk2(float a, float b) {
    return (uint)f2bf(a) | ((uint)f2bf(b) << 16);
}

// async global->LDS, 16B per lane. LDS dest must be wave-uniform base + lane*16.
__device__ __forceinline__ void g2l16(const ushort* g, ushort* l) {
    __builtin_amdgcn_global_load_lds(
        (const __attribute__((address_space(1))) void*)g,
        (__attribute__((address_space(3))) void*)l, 16, 0, 0);
}

// ---------------------------------------------------------------------------
// f32 -> bf16 elementwise
// ---------------------------------------------------------------------------
__global__ __launch_bounds__(256) void cvt_bf16_kernel(
    const float* __restrict__ in, ushort* __restrict__ out, int n)
{
    int i = (blockIdx.x * 256 + threadIdx.x) * 4;
    if (i >= n) return;
    float4 v = *(const float4*)(in + i);
    ushort4 o;
    o.x = f2bf(v.x); o.y = f2bf(v.y); o.z = f2bf(v.z); o.w = f2bf(v.w);
    *(ushort4*)(out + i) = o;
}

// ---------------------------------------------------------------------------
// transpose + convert: in f32 [K][N] -> out bf16 [N][K]; batched over z.
// ---------------------------------------------------------------------------
__global__ __launch_bounds__(256) void transpose_bf16_kernel(
    const float* __restrict__ in, ushort* __restrict__ out,
    int K, int N, long in_bstride, long out_bstride)
{
    __shared__ float t[32][33];
    const float* ib = in + (size_t)blockIdx.z * in_bstride;
    ushort* ob = out + (size_t)blockIdx.z * out_bstride;
    int n0 = blockIdx.x * 32, k0 = blockIdx.y * 32;
    int tid = threadIdx.x;
    int r = tid >> 3, c4 = (tid & 7) * 4;
    float4 v = *(const float4*)(ib + (size_t)(k0 + r) * N + n0 + c4);
    t[r][c4] = v.x; t[r][c4+1] = v.y; t[r][c4+2] = v.z; t[r][c4+3] = v.w;
    __syncthreads();
    int n = tid >> 3, kc = (tid & 7) * 4;
    ushort4 o;
    o.x = f2bf(t[kc+0][n]); o.y = f2bf(t[kc+1][n]);
    o.z = f2bf(t[kc+2][n]); o.w = f2bf(t[kc+3][n]);
    *(ushort4*)(ob + (size_t)(n0 + n) * K + k0 + kc) = o;
}

// fused Wq/Wk/Wv transpose: z in [0,48): mat = z>>4, head = z&15.
__global__ __launch_bounds__(256) void transpose_qkv_kernel(
    const float* __restrict__ Wq, const float* __restrict__ Wk,
    const float* __restrict__ Wv, ushort* __restrict__ outp)
{
    __shared__ float t[32][33];
    int z = blockIdx.z, mat = z >> 4, zz = z & 15;
    const float* ib = (mat == 0 ? Wq : (mat == 1 ? Wk : Wv)) + (size_t)zz * 65536;
    ushort* ob = outp + (size_t)mat * 1048576 + (size_t)zz * 65536;
    int n0 = blockIdx.x * 32, k0 = blockIdx.y * 32;
    int tid = threadIdx.x;
    int r = tid >> 3, c4 = (tid & 7) * 4;
    float4 v = *(const float4*)(ib + (size_t)(k0 + r) * 64 + n0 + c4);
    t[r][c4] = v.x; t[r][c4+1] = v.y; t[r][c4+2] = v.z; t[r][c4+3] = v.w;
    __syncthreads();
    int n = tid >> 3, kc = (tid & 7) * 4;
    ushort4 o;
    o.x = f2bf(t[kc+0][n]); o.y = f2bf(t[kc+1][n]);
    o.z = f2bf(t[kc+2][n]); o.w = f2bf(t[kc+3][n]);
    *(ushort4*)(ob + (size_t)(n0 + n) * 1024 + k0 + kc) = o;
}

// ---------------------------------------------------------------------------
// WIDE 128(M)x256(N) NT GEMM, bf16 MFMA, BK=32, 256 thr (4 waves of 64x128).
// DEPTH-2 COUNTED-VMCNT pipeline, 3 LDS buffers (72KB -> 2 blocks/CU),
// ONE barrier per K-tile:
//   prologue: stage tiles 0,1 (12 loads/thread in flight)
//   iter t: s_waitcnt vmcnt(6)  [tile t retired, t+1 flying -- never 0]
//           s_barrier (publish) ; stage t+2 -> buf[(t+2)%3]
//           ds_read buf[t%3] ; 32 MFMA
// WAR safe: buf[(t+2)%3] readers ran at iter t-1, their ds_reads retired by
// their MFMA consumers before this barrier. Split-K via blockIdx.z.
// ---------------------------------------------------------------------------
template<int OUT_BF16>
__global__ __launch_bounds__(256, 2) void gemm_ntw_kernel(
    const ushort* __restrict__ A, int lda,
    const ushort* __restrict__ Bt, int ldb,
    void* __restrict__ C, int ldc, int K,
    const float* __restrict__ bias,
    const float* __restrict__ resid, int relu,
    long aZoff, long bZoff, long cZoff)
{
    __shared__ __attribute__((aligned(16))) ushort As[3][4][128][8];
    __shared__ __attribute__((aligned(16))) ushort Bs[3][4][256][8];

    A  += (size_t)blockIdx.z * aZoff;
    Bt += (size_t)blockIdx.z * bZoff;
    char* Cb = (char*)C + (size_t)blockIdx.z * cZoff * (OUT_BF16 ? 2 : 4);

    int nwg  = gridDim.x * gridDim.y;
    int orig = blockIdx.y * gridDim.x + blockIdx.x;
    int work = (orig & 7) * (nwg >> 3) + (orig >> 3);
    int bx = work % gridDim.x, by = work / gridDim.x;

    int row0 = by * 128, col0 = bx * 256;
    int tid = threadIdx.x;
    int w = tid >> 6, l = tid & 63;
    int wr = (w >> 1) * 64, wc = (w & 1) * 128;

    int m0 = tid & 127, kc0 = tid >> 7;
    const ushort* gA = A  + (size_t)(row0 + m0) * lda + kc0 * 8;
    const ushort* gB = Bt + (size_t)(col0 + tid) * ldb;

    f32x4 acc[4][8];
    #pragma unroll
    for (int i = 0; i < 4; ++i)
        #pragma unroll
        for (int j = 0; j < 8; ++j) acc[i][j] = (f32x4){0.f, 0.f, 0.f, 0.f};

    const int NT = K >> 5;

    // prologue: stage tiles 0 and 1 (6 loads each per thread)
    #pragma unroll
    for (int tt = 0; tt < 2; ++tt) {
        if (tt < NT) {
            int k0 = tt << 5;
            g2l16(gA + k0,      &As[tt][kc0    ][m0][0]);
            g2l16(gA + k0 + 16, &As[tt][kc0 + 2][m0][0]);
            #pragma unroll
            for (int p = 0; p < 4; ++p)
                g2l16(gB + k0 + p*8, &Bs[tt][p][tid][0]);
        }
    }

    int cur = 0;                         // t % 3
    for (int t = 0; t < NT; ++t) {
        if (t + 1 < NT) asm volatile("s_waitcnt vmcnt(6)" ::: "memory");
        else            asm volatile("s_waitcnt vmcnt(0)" ::: "memory");
        __builtin_amdgcn_sched_barrier(0);
        __builtin_amdgcn_s_barrier();    // publish tile t to all waves
        __builtin_amdgcn_sched_barrier(0);

        if (t + 2 < NT) {                // stage tile t+2 into buf[(t+2)%3]
            int stg = cur + 2; if (stg >= 3) stg -= 3;
            int k0 = (t + 2) << 5;
            g2l16(gA + k0,      &As[stg][kc0    ][m0][0]);
            g2l16(gA + k0 + 16, &As[stg][kc0 + 2][m0][0]);
            #pragma unroll
            for (int p = 0; p < 4; ++p)
                g2l16(gB + k0 + p*8, &Bs[stg][p][tid][0]);
        }

        int kc = l >> 4;
        bf16x8 bfr[8];
        #pragma unroll
        for (int j = 0; j < 8; ++j)
            bfr[j] = *(const bf16x8*)&Bs[cur][kc][wc + j*16 + (l & 15)][0];
        #pragma unroll
        for (int i = 0; i < 4; ++i) {
            bf16x8 a = *(const bf16x8*)&As[cur][kc][wr + i*16 + (l & 15)][0];
            #pragma unroll
            for (int j = 0; j < 8; ++j)
                acc[i][j] = __builtin_amdgcn_mfma_f32_16x16x32_bf16(
                    a, bfr[j], acc[i][j], 0, 0, 0);
        }
        cur = (cur == 2) ? 0 : cur + 1;
    }

    #pragma unroll
    for (int i = 0; i < 4; ++i) {
        int rbase = row0 + wr + i*16 + (l >> 4) * 4;
        #pragma unroll
        for (int j = 0; j < 8; ++j) {
            int col = col0 + wc + j*16 + (l & 15);
            float bv = bias ? bias[col] : 0.f;
            #pragma unroll
            for (int r = 0; r < 4; ++r) {
                int row = rbase + r;
                float val = acc[i][j][r] + bv;
                if (resid) val += resid[(size_t)row * ldc + col];
                if (relu)  val = fmaxf(val, 0.f);
                if (OUT_BF16) ((ushort*)Cb)[(size_t)row * ldc + col] = f2bf(val);
                else          ((float*)Cb)[(size_t)row * ldc + col]  = val;
            }
        }
    }
}

// ---------------------------------------------------------------------------
// 128x128 NT GEMM, BK=32, 2-phase dbuf, 32KB LDS, split-K via blockIdx.z.
// (kept for Wo)
// ---------------------------------------------------------------------------
template<int OUT_BF16>
__global__ __launch_bounds__(256) void gemm_nt_kernel(
    const ushort* __restrict__ A, int lda,
    const ushort* __restrict__ Bt, int ldb,
    void* __restrict__ C, int ldc, int K,
    const float* __restrict__ bias,
    const float* __restrict__ resid, int relu,
    long aZoff, long bZoff, long cZoff)
{
    __shared__ __attribute__((aligned(16))) ushort As[2][4][128][8];
    __shared__ __attribute__((aligned(16))) ushort Bs[2][4][128][8];

    A  += (size_t)blockIdx.z * aZoff;
    Bt += (size_t)blockIdx.z * bZoff;
    char* Cb = (char*)C + (size_t)blockIdx.z * cZoff * (OUT_BF16 ? 2 : 4);

    int nwg  = gridDim.x * gridDim.y;
    int orig = blockIdx.y * gridDim.x + blockIdx.x;
    int work = (orig & 7) * (nwg >> 3) + (orig >> 3);
    int bx = work % gridDim.x, by = work / gridDim.x;

    int row0 = by * 128, col0 = bx * 128;
    int tid = threadIdx.x;
    int w = tid >> 6, l = tid & 63;
    int wr = (w >> 1) * 64, wc = (w & 1) * 64;

    int m0 = tid & 127, kc0 = tid >> 7;
    const ushort* ga0 = A  + (size_t)(row0 + m0) * lda + kc0 * 8;
    const ushort* gb0 = Bt + (size_t)(col0 + m0) * ldb + kc0 * 8;

    f32x4 acc[4][4];
    #pragma unroll
    for (int i = 0; i < 4; ++i)
        #pragma unroll
        for (int j = 0; j < 4; ++j) acc[i][j] = (f32x4){0.f, 0.f, 0.f, 0.f};

    const int NT = K >> 5;
    g2l16(ga0,      &As[0][kc0    ][m0][0]);
    g2l16(ga0 + 16, &As[0][kc0 + 2][m0][0]);
    g2l16(gb0,      &Bs[0][kc0    ][m0][0]);
    g2l16(gb0 + 16, &Bs[0][kc0 + 2][m0][0]);
    __syncthreads();

    int cur = 0;
    for (int t = 0; t < NT; ++t) {
        if (t + 1 < NT) {
            int k0 = (t + 1) << 5;
            g2l16(ga0 + k0,      &As[cur ^ 1][kc0    ][m0][0]);
            g2l16(ga0 + k0 + 16, &As[cur ^ 1][kc0 + 2][m0][0]);
            g2l16(gb0 + k0,      &Bs[cur ^ 1][kc0    ][m0][0]);
            g2l16(gb0 + k0 + 16, &Bs[cur ^ 1][kc0 + 2][m0][0]);
        }
        int kc = l >> 4;
        bf16x8 af[4], bfr[4];
        #pragma unroll
        for (int i = 0; i < 4; ++i)
            af[i] = *(const bf16x8*)&As[cur][kc][wr + i*16 + (l & 15)][0];
        #pragma unroll
        for (int j = 0; j < 4; ++j)
            bfr[j] = *(const bf16x8*)&Bs[cur][kc][wc + j*16 + (l & 15)][0];
        #pragma unroll
        for (int i = 0; i < 4; ++i)
            #pragma unroll
            for (int j = 0; j < 4; ++j)
                acc[i][j] = __builtin_amdgcn_mfma_f32_16x16x32_bf16(
                    af[i], bfr[j], acc[i][j], 0, 0, 0);
        __syncthreads();
        cur ^= 1;
    }

    #pragma unroll
    for (int i = 0; i < 4; ++i) {
        int rbase = row0 + wr + i*16 + (l >> 4) * 4;
        #pragma unroll
        for (int j = 0; j < 4; ++j) {
            int col = col0 + wc + j*16 + (l & 15);
            float bv = bias ? bias[col] : 0.f;
            #pragma unroll
            for (int r = 0; r < 4; ++r) {
                int row = rbase + r;
                float val = acc[i][j][r] + bv;
                if (resid) val += resid[(size_t)row * ldc + col];
                if (relu)  val = fmaxf(val, 0.f);
                if (OUT_BF16) ((ushort*)Cb)[(size_t)row * ldc + col] = f2bf(val);
                else          ((float*)Cb)[(size_t)row * ldc + col]  = val;
            }
        }
    }
}

// ---------------------------------------------------------------------------
// csum + vscale fused, Q-tile dbuf, XCD swizzle, hoisted K-fragments.
// ---------------------------------------------------------------------------
__global__ __launch_bounds__(256) void csumv_kernel(
    const ushort* __restrict__ qkv, ushort* __restrict__ vt)
{
    int nwg  = gridDim.x * gridDim.y;
    int orig = blockIdx.y * gridDim.x + blockIdx.x;
    int work = (orig & 7) * (nwg >> 3) + (orig >> 3);
    int bx = work % gridDim.x;
    int bh = work / gridDim.x;
    int b = bh >> 4, h = bh & 15;
    int s0 = bx * 128;
    const ushort* qb = qkv + (size_t)b * T_ * 3072 + h * 64;
    const ushort* kb = qb + 1024;
    const ushort* vb = qb + 2048;
    __shared__ __attribute__((aligned(16))) ushort Ks[8][128][8];
    __shared__ __attribute__((aligned(16))) ushort Qs[2][8][64][8];
    __shared__ float csl[128];
    __shared__ float t[64][65];
    int tid = threadIdx.x, w = tid >> 6, l = tid & 63;
    int scol = w * 32;
    int qq0 = l, kcA = w, kcB = w + 4;

    #pragma unroll
    for (int p = 0; p < 4; ++p) {
        int idx = tid + p * 256;
        int s = idx & 127, kc = idx >> 7;
        *(uint4*)&Ks[kc][s][0] =
            *(const uint4*)(kb + (size_t)(s0 + s) * 3072 + kc * 8);
    }
    g2l16(qb + (size_t)qq0 * 3072 + kcA * 8, &Qs[0][kcA][qq0][0]);
    g2l16(qb + (size_t)qq0 * 3072 + kcB * 8, &Qs[0][kcB][qq0][0]);
    __syncthreads();

    bf16x8 bfr[2][2];
    #pragma unroll
    for (int sj = 0; sj < 2; ++sj)
        #pragma unroll
        for (int ks = 0; ks < 2; ++ks)
            bfr[sj][ks] = *(const bf16x8*)&Ks[ks*4 + (l>>4)][scol + sj*16 + (l & 15)][0];

    float cs[2] = {0.f, 0.f};
    int cur = 0;
    for (int qt = 0; qt < T_ / 64; ++qt) {
        if (qt + 1 < T_ / 64) {
            const ushort* qn = qb + (size_t)((qt + 1) * 64 + qq0) * 3072;
            g2l16(qn + kcA * 8, &Qs[cur ^ 1][kcA][qq0][0]);
            g2l16(qn + kcB * 8, &Qs[cur ^ 1][kcB][qq0][0]);
        }
        bf16x8 af[4][2];
        #pragma unroll
        for (int qi = 0; qi < 4; ++qi)
            #pragma unroll
            for (int ks = 0; ks < 2; ++ks)
                af[qi][ks] = *(const bf16x8*)&Qs[cur][ks*4 + (l>>4)][qi*16 + (l & 15)][0];
        #pragma unroll
        for (int qi = 0; qi < 4; ++qi)
            #pragma unroll
            for (int sj = 0; sj < 2; ++sj) {
                f32x4 d = (f32x4){0.f, 0.f, 0.f, 0.f};
                #pragma unroll
                for (int ks = 0; ks < 2; ++ks)
                    d = __builtin_amdgcn_mfma_f32_16x16x32_bf16(
                        af[qi][ks], bfr[sj][ks], d, 0, 0, 0);
                cs[sj] += __expf(d[0]*0.125f) + __expf(d[1]*0.125f)
                        + __expf(d[2]*0.125f) + __expf(d[3]*0.125f);
            }
        __syncthreads();
        cur ^= 1;
    }
    #pragma unroll
    for (int sj = 0; sj < 2; ++sj) {
        float v = cs[sj];
        v += __shfl_down(v, 32, 64);
        v += __shfl_down(v, 16, 64);
        if (l < 16) csl[scol + sj*16 + l] = v;
    }
    __syncthreads();

    #pragma unroll
    for (int p2 = 0; p2 < 2; ++p2) {
        int sb = s0 + p2 * 64;
        #pragma unroll
        for (int p = 0; p < 2; ++p) {
            int idx = tid + p * 256;
            int s = idx >> 3, c0 = (idx & 7) * 8;
            uint4 raw = *(const uint4*)(vb + (size_t)(sb + s) * 3072 + c0);
            float rc = 1.0f / csl[p2 * 64 + s];
            ushort* u = (ushort*)&raw;
            #pragma unroll
            for (int i = 0; i < 8; ++i) t[s][c0 + i] = bf2f(u[i]) * rc;
        }
        __syncthreads();
        #pragma unroll
        for (int p = 0; p < 2; ++p) {
            int idx = tid + p * 256;
            int dv = idx >> 3, sc = (idx & 7) * 8;
            ushort o[8];
            #pragma unroll
            for (int i = 0; i < 8; ++i) o[i] = f2bf(t[sc + i][dv]);
            *(uint4*)(vt + ((size_t)bh * 64 + dv) * T_ + sb + sc) = *(uint4*)o;
        }
        __syncthreads();
    }
}

// ---------------------------------------------------------------------------
// PV: QBLK=128, K/V dbuf, Q in regs, XCD swizzle, swapped-QK^T packed-E.
// ---------------------------------------------------------------------------
__global__ __launch_bounds__(256) void attn_pv_kernel(
    const ushort* __restrict__ qkv, const ushort* __restrict__ vt,
    ushort* __restrict__ attn_o)
{
    int nwg  = gridDim.x * gridDim.y;
    int orig = blockIdx.y * gridDim.x + blockIdx.x;
    int work = (orig & 7) * (nwg >> 3) + (orig >> 3);
    int bx = work % gridDim.x;
    int bh = work / gridDim.x;
    int b = bh >> 4, h = bh & 15;
    int q0 = bx * 128;
    const ushort* qb = qkv + (size_t)b * T_ * 3072 + h * 64;
    const ushort* kb = qb + 1024;
    const ushort* vtb = vt + (size_t)bh * 64 * T_;
    __shared__ __attribute__((aligned(16))) ushort Ks[2][8][64][8];
    __shared__ __attribute__((aligned(16))) ushort Vs[2][8][64][8];
    __shared__ __attribute__((aligned(16))) ushort Es[128][64]; // [q][s], swizzled
    int tid = threadIdx.x, w = tid >> 6, l = tid & 63;
    int wq = w * 32;
    int kcA = w, kcB = w + 4;

    bf16x8 qf[2][2];
    #pragma unroll
    for (int qt = 0; qt < 2; ++qt)
        #pragma unroll
        for (int ks = 0; ks < 2; ++ks)
            qf[qt][ks] = *(const bf16x8*)(qb
                + (size_t)(q0 + wq + qt*16 + (l & 15)) * 3072
                + (ks*4 + (l >> 4)) * 8);

    f32x4 oacc[2][4];
    #pragma unroll
    for (int qt = 0; qt < 2; ++qt)
        #pragma unroll
        for (int j = 0; j < 4; ++j) oacc[qt][j] = (f32x4){0.f, 0.f, 0.f, 0.f};

    const int NT = T_ / 64;
    g2l16(kb + (size_t)l * 3072 + kcA * 8, &Ks[0][kcA][l][0]);
    g2l16(kb + (size_t)l * 3072 + kcB * 8, &Ks[0][kcB][l][0]);
    g2l16(vtb + (size_t)l * T_ + kcA * 8,  &Vs[0][kcA][l][0]);
    g2l16(vtb + (size_t)l * T_ + kcB * 8,  &Vs[0][kcB][l][0]);
    __syncthreads();

    int cur = 0;
    for (int st = 0; st < NT; ++st) {
        if (st + 1 < NT) {
            int s1 = (st + 1) * 64;
            g2l16(kb + (size_t)(s1 + l) * 3072 + kcA * 8, &Ks[cur^1][kcA][l][0]);
            g2l16(kb + (size_t)(s1 + l) * 3072 + kcB * 8, &Ks[cur^1][kcB][l][0]);
            g2l16(vtb + (size_t)l * T_ + s1 + kcA * 8,    &Vs[cur^1][kcA][l][0]);
            g2l16(vtb + (size_t)l * T_ + s1 + kcB * 8,    &Vs[cur^1][kcB][l][0]);
        }
        #pragma unroll
        for (int sj = 0; sj < 4; ++sj) {
            bf16x8 kfa[2];
            #pragma unroll
            for (int ks = 0; ks < 2; ++ks)
                kfa[ks] = *(const bf16x8*)&Ks[cur][ks*4 + (l>>4)][sj*16 + (l & 15)][0];
            #pragma unroll
            for (int qt = 0; qt < 2; ++qt) {
                f32x4 d = (f32x4){0.f, 0.f, 0.f, 0.f};
                #pragma unroll
                for (int ks = 0; ks < 2; ++ks)
                    d = __builtin_amdgcn_mfma_f32_16x16x32_bf16(
                        kfa[ks], qf[qt][ks], d, 0, 0, 0);
                int row = wq + qt*16 + (l & 15);
                int c16 = sj*2 + ((l >> 4) >> 1);
                int sub = (l >> 4) & 1;
                uint2 pv2;
                pv2.x = pk2(__expf(d[0]*0.125f), __expf(d[1]*0.125f));
                pv2.y = pk2(__expf(d[2]*0.125f), __expf(d[3]*0.125f));
                *(uint2*)((char*)Es + row*128 + ((c16 ^ (row & 7))*16 + sub*8)) = pv2;
            }
        }
        bf16x8 efa[2][2];
        #pragma unroll
        for (int qt = 0; qt < 2; ++qt) {
            int row = wq + qt*16 + (l & 15);
            #pragma unroll
            for (int ks = 0; ks < 2; ++ks)
                efa[qt][ks] = *(const bf16x8*)((char*)Es + row*128
                    + (((ks*4 + (l >> 4)) ^ (row & 7))*16));
        }
        #pragma unroll
        for (int j = 0; j < 4; ++j)
            #pragma unroll
            for (int ks = 0; ks < 2; ++ks) {
                bf16x8 vf = *(const bf16x8*)&Vs[cur][ks*4 + (l>>4)][j*16 + (l & 15)][0];
                #pragma unroll
                for (int qt = 0; qt < 2; ++qt)
                    oacc[qt][j] = __builtin_amdgcn_mfma_f32_16x16x32_bf16(
                        efa[qt][ks], vf, oacc[qt][j], 0, 0, 0);
            }
        __syncthreads();
        cur ^= 1;
    }

    #pragma unroll
    for (int qt = 0; qt < 2; ++qt)
        #pragma unroll
        for (int j = 0; j < 4; ++j)
            #pragma unroll
            for (int r = 0; r < 4; ++r) {
                int qq = q0 + wq + qt*16 + (l>>4)*4 + r;
                int dv = j*16 + (l & 15);
                attn_o[(size_t)(b*T_ + qq) * 1024 + h*64 + dv] = f2bf(oacc[qt][j][r]);
            }
}

// ---------------------------------------------------------------------------
// fused norm
// ---------------------------------------------------------------------------
__device__ __forceinline__ float block_reduce_sum_256(float v, float* tmp)
{
    #pragma unroll
    for (int off = 32; off; off >>= 1) v += __shfl_down(v, off, 64);
    int lane = threadIdx.x & 63, w = threadIdx.x >> 6;
    __syncthreads();
    if (lane == 0) tmp[w] = v;
    __syncthreads();
    return tmp[0] + tmp[1] + tmp[2] + tmp[3];
}

template<int Z>
__global__ __launch_bounds__(256) void normZ_fused_kernel(
    const ushort* __restrict__ parts, long zoff,
    const float* __restrict__ bias, const float* __restrict__ resid,
    float* __restrict__ outf, ushort* __restrict__ outb)
{
    __shared__ float tmp[4];
    int row = blockIdx.x;
    int tid = threadIdx.x;
    int c0 = tid * 4;
    size_t idx = (size_t)row * D_ + c0;
    float vals[4] = {0.f, 0.f, 0.f, 0.f};
    #pragma unroll
    for (int z = 0; z < Z; ++z) {
        ushort4 p = *(const ushort4*)&parts[idx + (size_t)z * zoff];
        vals[0] += bf2f(p.x); vals[1] += bf2f(p.y);
        vals[2] += bf2f(p.z); vals[3] += bf2f(p.w);
    }
    float4 rv = *(const float4*)&resid[idx];
    vals[0] += rv.x; vals[1] += rv.y; vals[2] += rv.z; vals[3] += rv.w;
    if (bias) {
        float4 bv = *(const float4*)&bias[c0];
        vals[0] += bv.x; vals[1] += bv.y; vals[2] += bv.z; vals[3] += bv.w;
    }
    float s = vals[0] + vals[1] + vals[2] + vals[3];
    s = block_reduce_sum_256(s, tmp);
    float m = s * (1.0f / (float)D_);
    float sq = 0.f;
    #pragma unroll
    for (int i = 0; i < 4; ++i) { float c = vals[i] - m; sq += c * c; }
    sq = block_reduce_sum_256(sq, tmp);
    float rs = rsqrtf(sq * (1.0f / (float)(D_ - 1)));
    float4 o;
    o.x = (vals[0] - m) * rs; o.y = (vals[1] - m) * rs;
    o.z = (vals[2] - m) * rs; o.w = (vals[3] - m) * rs;
    *(float4*)&outf[idx] = o;
    if (outb) {
        ushort4 ob;
        ob.x = f2bf(o.x); ob.y = f2bf(o.y); ob.z = f2bf(o.z); ob.w = f2bf(o.w);
        *(ushort4*)&outb[idx] = ob;
    }
}

// ---------------------------------------------------------------------------
extern "C" void kernel_launch(void* const* d_in, const int* in_sizes, int n_in,
                              void* d_out, int out_size, void* d_ws, size_t ws_size,
                              hipStream_t stream)
{
    const float* x  = (const float*)d_in[0];
    const float* Wq = (const float*)d_in[1];
    const float* Wk = (const float*)d_in[2];
    const float* Wv = (const float*)d_in[3];
    const float* Wo = (const float*)d_in[4];
    const float* W1 = (const float*)d_in[5];
    const float* b1 = (const float*)d_in[6];
    const float* W2 = (const float*)d_in[7];
    const float* b2 = (const float*)d_in[8];
    float* out = (float*)d_out;

    const size_t MB = (size_t)1 << 20;
    char* base = (char*)d_ws;
    ushort* qkv    = (ushort*)(base +   0*MB);  // 24MB  [QKV..PV]
    ushort* hid    = (ushort*)(base +   0*MB);  // 32MB  [W1..W2]
    ushort* xb     = (ushort*)(base +  24*MB);  //  8MB  [cvt..QKV]
    ushort* W2t    = (ushort*)(base +  32*MB);  //  8MB  [cvt..W2]
    ushort* Wqkvt  = (ushort*)(base +  40*MB);  //  6MB  [cvt..QKV]
    ushort* wpart  = (ushort*)(base +  40*MB);  // 32MB  [W2..norm2]
    ushort* vt     = (ushort*)(base +  46*MB);  //  8MB  [csumv..PV]
    ushort* Wot    = (ushort*)(base +  55*MB);  //  2MB  [cvt..Wo]
    ushort* W1t    = (ushort*)(base +  57*MB);  //  8MB  [cvt..W1]
    ushort* attn_o = (ushort*)(base +  65*MB);  //  8MB  [PV..Wo]
    ushort* wopart = (ushort*)(base +  73*MB);  // 16MB  [Wo..norm1]
    ushort* out1b  = (ushort*)(base +  89*MB);  //  8MB  [norm1..W1]
    float*  out1f  = (float*) (base +  97*MB);  // 16MB  [norm1..norm2]

    // 1. converts / transposes
    cvt_bf16_kernel<<<dim3(BT_*D_/1024), 256, 0, stream>>>(x, xb, BT_*D_);
    transpose_qkv_kernel<<<dim3(2, 32, 48), 256, 0, stream>>>(Wq, Wk, Wv, Wqkvt);
    transpose_bf16_kernel<<<dim3(32, 32, 1), 256, 0, stream>>>(
        Wo, Wot, 1024, 1024, 0, 0);
    transpose_bf16_kernel<<<dim3(128, 32, 1), 256, 0, stream>>>(
        W1, W1t, 1024, 4096, 0, 0);
    transpose_bf16_kernel<<<dim3(32, 128, 1), 256, 0, stream>>>(
        W2, W2t, 4096, 1024, 0, 0);

    // 2. QKV: wide tile depth-2, 384 blocks.
    gemm_ntw_kernel<1><<<dim3(3072/256, 4096/128, 1), 256, 0, stream>>>(
        xb, 1024, Wqkvt, 1024, qkv, 3072, 1024, nullptr, nullptr, 0, 0, 0, 0);
    // 3. colsum + V-scale/transpose fused
    csumv_kernel<<<dim3(T_/128, B_*H_), 256, 0, stream>>>(qkv, vt);
    // 4. PV
    attn_pv_kernel<<<dim3(T_/128, B_*H_), 256, 0, stream>>>(qkv, vt, attn_o);
    // 5. Wo split-K2 -> bf16 partials. 512 blocks.
    gemm_nt_kernel<1><<<dim3(1024/128, 4096/128, 2), 256, 0, stream>>>(
        attn_o, 1024, Wot, 1024, wopart, 1024, 512, nullptr, nullptr, 0,
        512, 512, (long)4096*1024);
    // 6. norm1 fused
    normZ_fused_kernel<2><<<dim3(BT_), 256, 0, stream>>>(
        wopart, (long)4096*1024, nullptr, x, out1f, out1b);
    // 7. FFN up + ReLU: wide tile depth-2, 512 blocks.
    gemm_ntw_kernel<1><<<dim3(4096/256, 4096/128, 1), 256, 0, stream>>>(
        out1b, 1024, W1t, 1024, hid, 4096, 1024, b1, nullptr, 1, 0, 0, 0);
    // 8. FFN down: wide tile depth-2 + split-K4. 512 blocks.
    gemm_ntw_kernel<1><<<dim3(1024/256, 4096/128, 4), 256, 0, stream>>>(
        hid, 4096, W2t, 4096, wpart, 1024, 1024, nullptr, nullptr, 0,
        1024, 1024, (long)4096*1024);
    // 9. norm2 fused: sum 4 partials + b2 + out1 resid -> out
    normZ_fused_kernel<4><<<dim3(BT_), 256, 0, stream>>>(
        wpart, (long)4096*1024, b2, out1f, out, nullptr);
}

// Round 16
// 358.932 us; speedup vs baseline: 1.0248x; 1.0248x over previous
//
#include <hip/hip_runtime.h>
#include <hip/hip_bf16.h>
#include <math.h>

#define B_  2
#define T_  2048
#define D_  1024
#define H_  16
#define DK_ 64
#define FF_ 4096
#define BT_ (B_*T_)

typedef __attribute__((ext_vector_type(8))) short bf16x8;
typedef __attribute__((ext_vector_type(4))) float f32x4;

__device__ __forceinline__ ushort f2bf(float f) {
    __hip_bfloat16 h = __float2bfloat16(f);
    return *reinterpret_cast<ushort*>(&h);
}
__device__ __forceinline__ float bf2f(ushort u) {
    __hip_bfloat16 h;
    *reinterpret_cast<ushort*>(&h) = u;
    return __bfloat162float(h);
}
__device__ __forceinline__ uint pk2(float a, float b) {
    return (uint)f2bf(a) | ((uint)f2bf(b) << 16);
}

// async global->LDS, 16B per lane. LDS dest must be wave-uniform base + lane*16.
__device__ __forceinline__ void g2l16(const ushort* g, ushort* l) {
    __builtin_amdgcn_global_load_lds(
        (const __attribute__((address_space(1))) void*)g,
        (__attribute__((address_space(3))) void*)l, 16, 0, 0);
}

// ---------------------------------------------------------------------------
// prep: ONE kernel for all input conversions/transposes.
// blockIdx.x ranges:
//   [0,1024):      Wo  f32[1024][1024] -> Wot  bf16[1024][1024] (32x32 tiles)
//   [1024,5120):   W1  f32[1024][4096] -> W1t  bf16[4096][1024]
//   [5120,9216):   W2  f32[4096][1024] -> W2t  bf16[1024][4096]
//   [9216,12288):  Wq/Wk/Wv per-head [1024][64] -> Wqkvt [3072][1024]
//   [12288,16384): x f32 -> xb bf16 (1024 elems per block)
// ---------------------------------------------------------------------------
__global__ __launch_bounds__(256) void prep_kernel(
    const float* __restrict__ x,
    const float* __restrict__ Wq, const float* __restrict__ Wk,
    const float* __restrict__ Wv, const float* __restrict__ Wo,
    const float* __restrict__ W1, const float* __restrict__ W2,
    ushort* __restrict__ xb, ushort* __restrict__ Wqkvt,
    ushort* __restrict__ Wot, ushort* __restrict__ W1t,
    ushort* __restrict__ W2t)
{
    int idx = blockIdx.x;
    int tid = threadIdx.x;
    if (idx >= 12288) {                       // x convert
        int i = (idx - 12288) * 1024 + tid * 4;
        float4 v = *(const float4*)(x + i);
        ushort4 o;
        o.x = f2bf(v.x); o.y = f2bf(v.y); o.z = f2bf(v.z); o.w = f2bf(v.w);
        *(ushort4*)(xb + i) = o;
        return;
    }
    __shared__ float t[32][33];
    const float* ib; ushort* ob; int K, N, n0, k0;
    if (idx < 1024) {                         // Wo
        ib = Wo; ob = Wot; K = 1024; N = 1024;
        n0 = (idx & 31) * 32; k0 = (idx >> 5) * 32;
    } else if (idx < 5120) {                  // W1
        int i2 = idx - 1024; ib = W1; ob = W1t; K = 1024; N = 4096;
        n0 = (i2 & 127) * 32; k0 = (i2 >> 7) * 32;
    } else if (idx < 9216) {                  // W2
        int i2 = idx - 5120; ib = W2; ob = W2t; K = 4096; N = 1024;
        n0 = (i2 & 31) * 32; k0 = (i2 >> 5) * 32;
    } else {                                  // Wq/Wk/Wv heads
        int i2 = idx - 9216; int z = i2 >> 6; int t2 = i2 & 63;
        int mat = z >> 4, zz = z & 15;
        ib = (mat == 0 ? Wq : (mat == 1 ? Wk : Wv)) + (size_t)zz * 65536;
        ob = Wqkvt + (size_t)mat * 1048576 + (size_t)zz * 65536;
        K = 1024; N = 64;
        n0 = (t2 & 1) * 32; k0 = (t2 >> 1) * 32;
    }
    int r = tid >> 3, c4 = (tid & 7) * 4;
    float4 v = *(const float4*)(ib + (size_t)(k0 + r) * N + n0 + c4);
    t[r][c4] = v.x; t[r][c4+1] = v.y; t[r][c4+2] = v.z; t[r][c4+3] = v.w;
    __syncthreads();
    int n = tid >> 3, kc = (tid & 7) * 4;
    ushort4 o;
    o.x = f2bf(t[kc+0][n]); o.y = f2bf(t[kc+1][n]);
    o.z = f2bf(t[kc+2][n]); o.w = f2bf(t[kc+3][n]);
    *(ushort4*)(ob + (size_t)(n0 + n) * K + k0 + kc) = o;
}

// ---------------------------------------------------------------------------
// WIDE 128(M)x256(N) NT GEMM, bf16 MFMA, BK=32, 256 thr (4 waves of 64x128).
// 2-phase dbuf, 48KB LDS. Split-K via blockIdx.z. (R14 best-known config.)
// ---------------------------------------------------------------------------
template<int OUT_BF16>
__global__ __launch_bounds__(256, 2) void gemm_ntw_kernel(
    const ushort* __restrict__ A, int lda,
    const ushort* __restrict__ Bt, int ldb,
    void* __restrict__ C, int ldc, int K,
    const float* __restrict__ bias,
    const float* __restrict__ resid, int relu,
    long aZoff, long bZoff, long cZoff)
{
    __shared__ __attribute__((aligned(16))) ushort As[2][4][128][8];
    __shared__ __attribute__((aligned(16))) ushort Bs[2][4][256][8];

    A  += (size_t)blockIdx.z * aZoff;
    Bt += (size_t)blockIdx.z * bZoff;
    char* Cb = (char*)C + (size_t)blockIdx.z * cZoff * (OUT_BF16 ? 2 : 4);

    int nwg  = gridDim.x * gridDim.y;
    int orig = blockIdx.y * gridDim.x + blockIdx.x;
    int work = (orig & 7) * (nwg >> 3) + (orig >> 3);
    int bx = work % gridDim.x, by = work / gridDim.x;

    int row0 = by * 128, col0 = bx * 256;
    int tid = threadIdx.x;
    int w = tid >> 6, l = tid & 63;
    int wr = (w >> 1) * 64, wc = (w & 1) * 128;

    int m0 = tid & 127, kc0 = tid >> 7;
    const ushort* gA = A  + (size_t)(row0 + m0) * lda + kc0 * 8;
    const ushort* gB = Bt + (size_t)(col0 + tid) * ldb;

    f32x4 acc[4][8];
    #pragma unroll
    for (int i = 0; i < 4; ++i)
        #pragma unroll
        for (int j = 0; j < 8; ++j) acc[i][j] = (f32x4){0.f, 0.f, 0.f, 0.f};

    const int NT = K >> 5;
    g2l16(gA,      &As[0][kc0    ][m0][0]);
    g2l16(gA + 16, &As[0][kc0 + 2][m0][0]);
    #pragma unroll
    for (int p = 0; p < 4; ++p)
        g2l16(gB + p*8, &Bs[0][p][tid][0]);
    __syncthreads();

    int cur = 0;
    for (int t = 0; t < NT; ++t) {
        if (t + 1 < NT) {
            int k0 = (t + 1) << 5;
            g2l16(gA + k0,      &As[cur ^ 1][kc0    ][m0][0]);
            g2l16(gA + k0 + 16, &As[cur ^ 1][kc0 + 2][m0][0]);
            #pragma unroll
            for (int p = 0; p < 4; ++p)
                g2l16(gB + k0 + p*8, &Bs[cur ^ 1][p][tid][0]);
        }
        int kc = l >> 4;
        bf16x8 bfr[8];
        #pragma unroll
        for (int j = 0; j < 8; ++j)
            bfr[j] = *(const bf16x8*)&Bs[cur][kc][wc + j*16 + (l & 15)][0];
        #pragma unroll
        for (int i = 0; i < 4; ++i) {
            bf16x8 a = *(const bf16x8*)&As[cur][kc][wr + i*16 + (l & 15)][0];
            #pragma unroll
            for (int j = 0; j < 8; ++j)
                acc[i][j] = __builtin_amdgcn_mfma_f32_16x16x32_bf16(
                    a, bfr[j], acc[i][j], 0, 0, 0);
        }
        __syncthreads();
        cur ^= 1;
    }

    #pragma unroll
    for (int i = 0; i < 4; ++i) {
        int rbase = row0 + wr + i*16 + (l >> 4) * 4;
        #pragma unroll
        for (int j = 0; j < 8; ++j) {
            int col = col0 + wc + j*16 + (l & 15);
            float bv = bias ? bias[col] : 0.f;
            #pragma unroll
            for (int r = 0; r < 4; ++r) {
                int row = rbase + r;
                float val = acc[i][j][r] + bv;
                if (resid) val += resid[(size_t)row * ldc + col];
                if (relu)  val = fmaxf(val, 0.f);
                if (OUT_BF16) ((ushort*)Cb)[(size_t)row * ldc + col] = f2bf(val);
                else          ((float*)Cb)[(size_t)row * ldc + col]  = val;
            }
        }
    }
}

// ---------------------------------------------------------------------------
// 128x128 NT GEMM, BK=32, 2-phase dbuf, 32KB LDS, split-K via blockIdx.z.
// (kept for Wo)
// ---------------------------------------------------------------------------
template<int OUT_BF16>
__global__ __launch_bounds__(256) void gemm_nt_kernel(
    const ushort* __restrict__ A, int lda,
    const ushort* __restrict__ Bt, int ldb,
    void* __restrict__ C, int ldc, int K,
    const float* __restrict__ bias,
    const float* __restrict__ resid, int relu,
    long aZoff, long bZoff, long cZoff)
{
    __shared__ __attribute__((aligned(16))) ushort As[2][4][128][8];
    __shared__ __attribute__((aligned(16))) ushort Bs[2][4][128][8];

    A  += (size_t)blockIdx.z * aZoff;
    Bt += (size_t)blockIdx.z * bZoff;
    char* Cb = (char*)C + (size_t)blockIdx.z * cZoff * (OUT_BF16 ? 2 : 4);

    int nwg  = gridDim.x * gridDim.y;
    int orig = blockIdx.y * gridDim.x + blockIdx.x;
    int work = (orig & 7) * (nwg >> 3) + (orig >> 3);
    int bx = work % gridDim.x, by = work / gridDim.x;

    int row0 = by * 128, col0 = bx * 128;
    int tid = threadIdx.x;
    int w = tid >> 6, l = tid & 63;
    int wr = (w >> 1) * 64, wc = (w & 1) * 64;

    int m0 = tid & 127, kc0 = tid >> 7;
    const ushort* ga0 = A  + (size_t)(row0 + m0) * lda + kc0 * 8;
    const ushort* gb0 = Bt + (size_t)(col0 + m0) * ldb + kc0 * 8;

    f32x4 acc[4][4];
    #pragma unroll
    for (int i = 0; i < 4; ++i)
        #pragma unroll
        for (int j = 0; j < 4; ++j) acc[i][j] = (f32x4){0.f, 0.f, 0.f, 0.f};

    const int NT = K >> 5;
    g2l16(ga0,      &As[0][kc0    ][m0][0]);
    g2l16(ga0 + 16, &As[0][kc0 + 2][m0][0]);
    g2l16(gb0,      &Bs[0][kc0    ][m0][0]);
    g2l16(gb0 + 16, &Bs[0][kc0 + 2][m0][0]);
    __syncthreads();

    int cur = 0;
    for (int t = 0; t < NT; ++t) {
        if (t + 1 < NT) {
            int k0 = (t + 1) << 5;
            g2l16(ga0 + k0,      &As[cur ^ 1][kc0    ][m0][0]);
            g2l16(ga0 + k0 + 16, &As[cur ^ 1][kc0 + 2][m0][0]);
            g2l16(gb0 + k0,      &Bs[cur ^ 1][kc0    ][m0][0]);
            g2l16(gb0 + k0 + 16, &Bs[cur ^ 1][kc0 + 2][m0][0]);
        }
        int kc = l >> 4;
        bf16x8 af[4], bfr[4];
        #pragma unroll
        for (int i = 0; i < 4; ++i)
            af[i] = *(const bf16x8*)&As[cur][kc][wr + i*16 + (l & 15)][0];
        #pragma unroll
        for (int j = 0; j < 4; ++j)
            bfr[j] = *(const bf16x8*)&Bs[cur][kc][wc + j*16 + (l & 15)][0];
        #pragma unroll
        for (int i = 0; i < 4; ++i)
            #pragma unroll
            for (int j = 0; j < 4; ++j)
                acc[i][j] = __builtin_amdgcn_mfma_f32_16x16x32_bf16(
                    af[i], bfr[j], acc[i][j], 0, 0, 0);
        __syncthreads();
        cur ^= 1;
    }

    #pragma unroll
    for (int i = 0; i < 4; ++i) {
        int rbase = row0 + wr + i*16 + (l >> 4) * 4;
        #pragma unroll
        for (int j = 0; j < 4; ++j) {
            int col = col0 + wc + j*16 + (l & 15);
            float bv = bias ? bias[col] : 0.f;
            #pragma unroll
            for (int r = 0; r < 4; ++r) {
                int row = rbase + r;
                float val = acc[i][j][r] + bv;
                if (resid) val += resid[(size_t)row * ldc + col];
                if (relu)  val = fmaxf(val, 0.f);
                if (OUT_BF16) ((ushort*)Cb)[(size_t)row * ldc + col] = f2bf(val);
                else          ((float*)Cb)[(size_t)row * ldc + col]  = val;
            }
        }
    }
}

// ---------------------------------------------------------------------------
// csum + vscale fused, Q-tile dbuf, XCD swizzle, hoisted K-fragments.
// ---------------------------------------------------------------------------
__global__ __launch_bounds__(256) void csumv_kernel(
    const ushort* __restrict__ qkv, ushort* __restrict__ vt)
{
    int nwg  = gridDim.x * gridDim.y;
    int orig = blockIdx.y * gridDim.x + blockIdx.x;
    int work = (orig & 7) * (nwg >> 3) + (orig >> 3);
    int bx = work % gridDim.x;
    int bh = work / gridDim.x;
    int b = bh >> 4, h = bh & 15;
    int s0 = bx * 128;
    const ushort* qb = qkv + (size_t)b * T_ * 3072 + h * 64;
    const ushort* kb = qb + 1024;
    const ushort* vb = qb + 2048;
    __shared__ __attribute__((aligned(16))) ushort Ks[8][128][8];
    __shared__ __attribute__((aligned(16))) ushort Qs[2][8][64][8];
    __shared__ float csl[128];
    __shared__ float t[64][65];
    int tid = threadIdx.x, w = tid >> 6, l = tid & 63;
    int scol = w * 32;
    int qq0 = l, kcA = w, kcB = w + 4;

    #pragma unroll
    for (int p = 0; p < 4; ++p) {
        int idx = tid + p * 256;
        int s = idx & 127, kc = idx >> 7;
        *(uint4*)&Ks[kc][s][0] =
            *(const uint4*)(kb + (size_t)(s0 + s) * 3072 + kc * 8);
    }
    g2l16(qb + (size_t)qq0 * 3072 + kcA * 8, &Qs[0][kcA][qq0][0]);
    g2l16(qb + (size_t)qq0 * 3072 + kcB * 8, &Qs[0][kcB][qq0][0]);
    __syncthreads();

    bf16x8 bfr[2][2];
    #pragma unroll
    for (int sj = 0; sj < 2; ++sj)
        #pragma unroll
        for (int ks = 0; ks < 2; ++ks)
            bfr[sj][ks] = *(const bf16x8*)&Ks[ks*4 + (l>>4)][scol + sj*16 + (l & 15)][0];

    float cs[2] = {0.f, 0.f};
    int cur = 0;
    for (int qt = 0; qt < T_ / 64; ++qt) {
        if (qt + 1 < T_ / 64) {
            const ushort* qn = qb + (size_t)((qt + 1) * 64 + qq0) * 3072;
            g2l16(qn + kcA * 8, &Qs[cur ^ 1][kcA][qq0][0]);
            g2l16(qn + kcB * 8, &Qs[cur ^ 1][kcB][qq0][0]);
        }
        bf16x8 af[4][2];
        #pragma unroll
        for (int qi = 0; qi < 4; ++qi)
            #pragma unroll
            for (int ks = 0; ks < 2; ++ks)
                af[qi][ks] = *(const bf16x8*)&Qs[cur][ks*4 + (l>>4)][qi*16 + (l & 15)][0];
        #pragma unroll
        for (int qi = 0; qi < 4; ++qi)
            #pragma unroll
            for (int sj = 0; sj < 2; ++sj) {
                f32x4 d = (f32x4){0.f, 0.f, 0.f, 0.f};
                #pragma unroll
                for (int ks = 0; ks < 2; ++ks)
                    d = __builtin_amdgcn_mfma_f32_16x16x32_bf16(
                        af[qi][ks], bfr[sj][ks], d, 0, 0, 0);
                cs[sj] += __expf(d[0]*0.125f) + __expf(d[1]*0.125f)
                        + __expf(d[2]*0.125f) + __expf(d[3]*0.125f);
            }
        __syncthreads();
        cur ^= 1;
    }
    #pragma unroll
    for (int sj = 0; sj < 2; ++sj) {
        float v = cs[sj];
        v += __shfl_down(v, 32, 64);
        v += __shfl_down(v, 16, 64);
        if (l < 16) csl[scol + sj*16 + l] = v;
    }
    __syncthreads();

    #pragma unroll
    for (int p2 = 0; p2 < 2; ++p2) {
        int sb = s0 + p2 * 64;
        #pragma unroll
        for (int p = 0; p < 2; ++p) {
            int idx = tid + p * 256;
            int s = idx >> 3, c0 = (idx & 7) * 8;
            uint4 raw = *(const uint4*)(vb + (size_t)(sb + s) * 3072 + c0);
            float rc = 1.0f / csl[p2 * 64 + s];
            ushort* u = (ushort*)&raw;
            #pragma unroll
            for (int i = 0; i < 8; ++i) t[s][c0 + i] = bf2f(u[i]) * rc;
        }
        __syncthreads();
        #pragma unroll
        for (int p = 0; p < 2; ++p) {
            int idx = tid + p * 256;
            int dv = idx >> 3, sc = (idx & 7) * 8;
            ushort o[8];
            #pragma unroll
            for (int i = 0; i < 8; ++i) o[i] = f2bf(t[sc + i][dv]);
            *(uint4*)(vt + ((size_t)bh * 64 + dv) * T_ + sb + sc) = *(uint4*)o;
        }
        __syncthreads();
    }
}

// ---------------------------------------------------------------------------
// PV: QBLK=128, K/V dbuf, Q in regs, XCD swizzle, swapped-QK^T packed-E.
// ---------------------------------------------------------------------------
__global__ __launch_bounds__(256) void attn_pv_kernel(
    const ushort* __restrict__ qkv, const ushort* __restrict__ vt,
    ushort* __restrict__ attn_o)
{
    int nwg  = gridDim.x * gridDim.y;
    int orig = blockIdx.y * gridDim.x + blockIdx.x;
    int work = (orig & 7) * (nwg >> 3) + (orig >> 3);
    int bx = work % gridDim.x;
    int bh = work / gridDim.x;
    int b = bh >> 4, h = bh & 15;
    int q0 = bx * 128;
    const ushort* qb = qkv + (size_t)b * T_ * 3072 + h * 64;
    const ushort* kb = qb + 1024;
    const ushort* vtb = vt + (size_t)bh * 64 * T_;
    __shared__ __attribute__((aligned(16))) ushort Ks[2][8][64][8];
    __shared__ __attribute__((aligned(16))) ushort Vs[2][8][64][8];
    __shared__ __attribute__((aligned(16))) ushort Es[128][64]; // [q][s], swizzled
    int tid = threadIdx.x, w = tid >> 6, l = tid & 63;
    int wq = w * 32;
    int kcA = w, kcB = w + 4;

    bf16x8 qf[2][2];
    #pragma unroll
    for (int qt = 0; qt < 2; ++qt)
        #pragma unroll
        for (int ks = 0; ks < 2; ++ks)
            qf[qt][ks] = *(const bf16x8*)(qb
                + (size_t)(q0 + wq + qt*16 + (l & 15)) * 3072
                + (ks*4 + (l >> 4)) * 8);

    f32x4 oacc[2][4];
    #pragma unroll
    for (int qt = 0; qt < 2; ++qt)
        #pragma unroll
        for (int j = 0; j < 4; ++j) oacc[qt][j] = (f32x4){0.f, 0.f, 0.f, 0.f};

    const int NT = T_ / 64;
    g2l16(kb + (size_t)l * 3072 + kcA * 8, &Ks[0][kcA][l][0]);
    g2l16(kb + (size_t)l * 3072 + kcB * 8, &Ks[0][kcB][l][0]);
    g2l16(vtb + (size_t)l * T_ + kcA * 8,  &Vs[0][kcA][l][0]);
    g2l16(vtb + (size_t)l * T_ + kcB * 8,  &Vs[0][kcB][l][0]);
    __syncthreads();

    int cur = 0;
    for (int st = 0; st < NT; ++st) {
        if (st + 1 < NT) {
            int s1 = (st + 1) * 64;
            g2l16(kb + (size_t)(s1 + l) * 3072 + kcA * 8, &Ks[cur^1][kcA][l][0]);
            g2l16(kb + (size_t)(s1 + l) * 3072 + kcB * 8, &Ks[cur^1][kcB][l][0]);
            g2l16(vtb + (size_t)l * T_ + s1 + kcA * 8,    &Vs[cur^1][kcA][l][0]);
            g2l16(vtb + (size_t)l * T_ + s1 + kcB * 8,    &Vs[cur^1][kcB][l][0]);
        }
        #pragma unroll
        for (int sj = 0; sj < 4; ++sj) {
            bf16x8 kfa[2];
            #pragma unroll
            for (int ks = 0; ks < 2; ++ks)
                kfa[ks] = *(const bf16x8*)&Ks[cur][ks*4 + (l>>4)][sj*16 + (l & 15)][0];
            #pragma unroll
            for (int qt = 0; qt < 2; ++qt) {
                f32x4 d = (f32x4){0.f, 0.f, 0.f, 0.f};
                #pragma unroll
                for (int ks = 0; ks < 2; ++ks)
                    d = __builtin_amdgcn_mfma_f32_16x16x32_bf16(
                        kfa[ks], qf[qt][ks], d, 0, 0, 0);
                int row = wq + qt*16 + (l & 15);
                int c16 = sj*2 + ((l >> 4) >> 1);
                int sub = (l >> 4) & 1;
                uint2 pv2;
                pv2.x = pk2(__expf(d[0]*0.125f), __expf(d[1]*0.125f));
                pv2.y = pk2(__expf(d[2]*0.125f), __expf(d[3]*0.125f));
                *(uint2*)((char*)Es + row*128 + ((c16 ^ (row & 7))*16 + sub*8)) = pv2;
            }
        }
        bf16x8 efa[2][2];
        #pragma unroll
        for (int qt = 0; qt < 2; ++qt) {
            int row = wq + qt*16 + (l & 15);
            #pragma unroll
            for (int ks = 0; ks < 2; ++ks)
                efa[qt][ks] = *(const bf16x8*)((char*)Es + row*128
                    + (((ks*4 + (l >> 4)) ^ (row & 7))*16));
        }
        #pragma unroll
        for (int j = 0; j < 4; ++j)
            #pragma unroll
            for (int ks = 0; ks < 2; ++ks) {
                bf16x8 vf = *(const bf16x8*)&Vs[cur][ks*4 + (l>>4)][j*16 + (l & 15)][0];
                #pragma unroll
                for (int qt = 0; qt < 2; ++qt)
                    oacc[qt][j] = __builtin_amdgcn_mfma_f32_16x16x32_bf16(
                        efa[qt][ks], vf, oacc[qt][j], 0, 0, 0);
            }
        __syncthreads();
        cur ^= 1;
    }

    #pragma unroll
    for (int qt = 0; qt < 2; ++qt)
        #pragma unroll
        for (int j = 0; j < 4; ++j)
            #pragma unroll
            for (int r = 0; r < 4; ++r) {
                int qq = q0 + wq + qt*16 + (l>>4)*4 + r;
                int dv = j*16 + (l & 15);
                attn_o[(size_t)(b*T_ + qq) * 1024 + h*64 + dv] = f2bf(oacc[qt][j][r]);
            }
}

// ---------------------------------------------------------------------------
// fused norm
// ---------------------------------------------------------------------------
__device__ __forceinline__ float block_reduce_sum_256(float v, float* tmp)
{
    #pragma unroll
    for (int off = 32; off; off >>= 1) v += __shfl_down(v, off, 64);
    int lane = threadIdx.x & 63, w = threadIdx.x >> 6;
    __syncthreads();
    if (lane == 0) tmp[w] = v;
    __syncthreads();
    return tmp[0] + tmp[1] + tmp[2] + tmp[3];
}

template<int Z>
__global__ __launch_bounds__(256) void normZ_fused_kernel(
    const ushort* __restrict__ parts, long zoff,
    const float* __restrict__ bias, const float* __restrict__ resid,
    float* __restrict__ outf, ushort* __restrict__ outb)
{
    __shared__ float tmp[4];
    int row = blockIdx.x;
    int tid = threadIdx.x;
    int c0 = tid * 4;
    size_t idx = (size_t)row * D_ + c0;
    float vals[4] = {0.f, 0.f, 0.f, 0.f};
    #pragma unroll
    for (int z = 0; z < Z; ++z) {
        ushort4 p = *(const ushort4*)&parts[idx + (size_t)z * zoff];
        vals[0] += bf2f(p.x); vals[1] += bf2f(p.y);
        vals[2] += bf2f(p.z); vals[3] += bf2f(p.w);
    }
    float4 rv = *(const float4*)&resid[idx];
    vals[0] += rv.x; vals[1] += rv.y; vals[2] += rv.z; vals[3] += rv.w;
    if (bias) {
        float4 bv = *(const float4*)&bias[c0];
        vals[0] += bv.x; vals[1] += bv.y; vals[2] += bv.z; vals[3] += bv.w;
    }
    float s = vals[0] + vals[1] + vals[2] + vals[3];
    s = block_reduce_sum_256(s, tmp);
    float m = s * (1.0f / (float)D_);
    float sq = 0.f;
    #pragma unroll
    for (int i = 0; i < 4; ++i) { float c = vals[i] - m; sq += c * c; }
    sq = block_reduce_sum_256(sq, tmp);
    float rs = rsqrtf(sq * (1.0f / (float)(D_ - 1)));
    float4 o;
    o.x = (vals[0] - m) * rs; o.y = (vals[1] - m) * rs;
    o.z = (vals[2] - m) * rs; o.w = (vals[3] - m) * rs;
    *(float4*)&outf[idx] = o;
    if (outb) {
        ushort4 ob;
        ob.x = f2bf(o.x); ob.y = f2bf(o.y); ob.z = f2bf(o.z); ob.w = f2bf(o.w);
        *(ushort4*)&outb[idx] = ob;
    }
}

// ---------------------------------------------------------------------------
extern "C" void kernel_launch(void* const* d_in, const int* in_sizes, int n_in,
                              void* d_out, int out_size, void* d_ws, size_t ws_size,
                              hipStream_t stream)
{
    const float* x  = (const float*)d_in[0];
    const float* Wq = (const float*)d_in[1];
    const float* Wk = (const float*)d_in[2];
    const float* Wv = (const float*)d_in[3];
    const float* Wo = (const float*)d_in[4];
    const float* W1 = (const float*)d_in[5];
    const float* b1 = (const float*)d_in[6];
    const float* W2 = (const float*)d_in[7];
    const float* b2 = (const float*)d_in[8];
    float* out = (float*)d_out;

    const size_t MB = (size_t)1 << 20;
    char* base = (char*)d_ws;
    ushort* qkv    = (ushort*)(base +   0*MB);  // 24MB  [QKV..PV]
    ushort* hid    = (ushort*)(base +   0*MB);  // 32MB  [W1..W2]
    ushort* xb     = (ushort*)(base +  24*MB);  //  8MB  [prep..QKV]
    ushort* W2t    = (ushort*)(base +  32*MB);  //  8MB  [prep..W2]
    ushort* Wqkvt  = (ushort*)(base +  40*MB);  //  6MB  [prep..QKV]
    ushort* wpart  = (ushort*)(base +  40*MB);  // 32MB  [W2..norm2]
    ushort* vt     = (ushort*)(base +  46*MB);  //  8MB  [csumv..PV]
    ushort* Wot    = (ushort*)(base +  55*MB);  //  2MB  [prep..Wo]
    ushort* W1t    = (ushort*)(base +  57*MB);  //  8MB  [prep..W1]
    ushort* attn_o = (ushort*)(base +  65*MB);  //  8MB  [PV..Wo]
    ushort* wopart = (ushort*)(base +  73*MB);  // 16MB  [Wo..norm1]
    ushort* out1b  = (ushort*)(base +  89*MB);  //  8MB  [norm1..W1]
    float*  out1f  = (float*) (base +  97*MB);  // 16MB  [norm1..norm2]

    // 1. single fused prep: all converts + transposes
    prep_kernel<<<dim3(16384), 256, 0, stream>>>(
        x, Wq, Wk, Wv, Wo, W1, W2, xb, Wqkvt, Wot, W1t, W2t);

    // 2. QKV: wide tile, 384 blocks.
    gemm_ntw_kernel<1><<<dim3(3072/256, 4096/128, 1), 256, 0, stream>>>(
        xb, 1024, Wqkvt, 1024, qkv, 3072, 1024, nullptr, nullptr, 0, 0, 0, 0);
    // 3. colsum + V-scale/transpose fused
    csumv_kernel<<<dim3(T_/128, B_*H_), 256, 0, stream>>>(qkv, vt);
    // 4. PV
    attn_pv_kernel<<<dim3(T_/128, B_*H_), 256, 0, stream>>>(qkv, vt, attn_o);
    // 5. Wo split-K2 -> bf16 partials. 512 blocks.
    gemm_nt_kernel<1><<<dim3(1024/128, 4096/128, 2), 256, 0, stream>>>(
        attn_o, 1024, Wot, 1024, wopart, 1024, 512, nullptr, nullptr, 0,
        512, 512, (long)4096*1024);
    // 6. norm1 fused
    normZ_fused_kernel<2><<<dim3(BT_), 256, 0, stream>>>(
        wopart, (long)4096*1024, nullptr, x, out1f, out1b);
    // 7. FFN up + ReLU: wide tile, 512 blocks.
    gemm_ntw_kernel<1><<<dim3(4096/256, 4096/128, 1), 256, 0, stream>>>(
        out1b, 1024, W1t, 1024, hid, 4096, 1024, b1, nullptr, 1, 0, 0, 0);
    // 8. FFN down: wide tile + split-K4. 512 blocks.
    gemm_ntw_kernel<1><<<dim3(1024/256, 4096/128, 4), 256, 0, stream>>>(
        hid, 4096, W2t, 4096, wpart, 1024, 1024, nullptr, nullptr, 0,
        1024, 1024, (long)4096*1024);
    // 9. norm2 fused: sum 4 partials + b2 + out1 resid -> out
    normZ_fused_kernel<4><<<dim3(BT_), 256, 0, stream>>>(
        wpart, (long)4096*1024, b2, out1f, out, nullptr);
}

// Round 17
// 358.057 us; speedup vs baseline: 1.0273x; 1.0024x over previous
//
#include <hip/hip_runtime.h>
#include <hip/hip_bf16.h>
#include <math.h>

#define B_  2
#define T_  2048
#define D_  1024
#define H_  16
#define DK_ 64
#define FF_ 4096
#define BT_ (B_*T_)

typedef __attribute__((ext_vector_type(8))) short bf16x8;
typedef __attribute__((ext_vector_type(4))) float f32x4;

__device__ __forceinline__ ushort f2bf(float f) {
    __hip_bfloat16 h = __float2bfloat16(f);
    return *reinterpret_cast<ushort*>(&h);
}
__device__ __forceinline__ float bf2f(ushort u) {
    __hip_bfloat16 h;
    *reinterpret_cast<ushort*>(&h) = u;
    return __bfloat162float(h);
}
__device__ __forceinline__ uint pk2(float a, float b) {
    return (uint)f2bf(a) | ((uint)f2bf(b) << 16);
}

// async global->LDS, 16B per lane. LDS dest must be wave-uniform base + lane*16.
__device__ __forceinline__ void g2l16(const ushort* g, ushort* l) {
    __builtin_amdgcn_global_load_lds(
        (const __attribute__((address_space(1))) void*)g,
        (__attribute__((address_space(3))) void*)l, 16, 0, 0);
}

// 2D-rect XCD swizzle: partition (gx x gy) grid into 8 rectangles; XCD k owns
// one rectangle -> per-XCD A/B panel working set fits the 4MB XCD L2.
// Bijective: (xcd = orig&7, i = orig>>3) <-> orig.
__device__ __forceinline__ void xcd_rect(int gx, int gy, int* bx, int* by) {
    int orig = blockIdx.y * gx + blockIdx.x;
    int xg = (gx & 1) ? 1 : 2;
    int rw = gx / xg, rh = (gy * xg) >> 3;     // gy / (8/xg)
    int xcd = orig & 7, i = orig >> 3;
    *bx = (xcd % xg) * rw + i % rw;
    *by = (xcd / xg) * rh + i / rw;
}

// ---------------------------------------------------------------------------
// prep: ONE kernel for all input conversions/transposes.
// blockIdx.x ranges:
//   [0,1024):      Wo  f32[1024][1024] -> Wot  bf16[1024][1024] (32x32 tiles)
//   [1024,5120):   W1  f32[1024][4096] -> W1t  bf16[4096][1024]
//   [5120,9216):   W2  f32[4096][1024] -> W2t  bf16[1024][4096]
//   [9216,12288):  Wq/Wk/Wv per-head [1024][64] -> Wqkvt [3072][1024]
//   [12288,14336): x f32 -> xb bf16 (2048 elems per block)
// ---------------------------------------------------------------------------
__global__ __launch_bounds__(256) void prep_kernel(
    const float* __restrict__ x,
    const float* __restrict__ Wq, const float* __restrict__ Wk,
    const float* __restrict__ Wv, const float* __restrict__ Wo,
    const float* __restrict__ W1, const float* __restrict__ W2,
    ushort* __restrict__ xb, ushort* __restrict__ Wqkvt,
    ushort* __restrict__ Wot, ushort* __restrict__ W1t,
    ushort* __restrict__ W2t)
{
    int idx = blockIdx.x;
    int tid = threadIdx.x;
    if (idx >= 12288) {                       // x convert, 2048/block
        int i = (idx - 12288) * 2048 + tid * 4;
        #pragma unroll
        for (int p = 0; p < 2; ++p) {
            float4 v = *(const float4*)(x + i + p * 1024);
            ushort4 o;
            o.x = f2bf(v.x); o.y = f2bf(v.y); o.z = f2bf(v.z); o.w = f2bf(v.w);
            *(ushort4*)(xb + i + p * 1024) = o;
        }
        return;
    }
    __shared__ float t[32][33];
    const float* ib; ushort* ob; int K, N, n0, k0;
    if (idx < 1024) {                         // Wo
        ib = Wo; ob = Wot; K = 1024; N = 1024;
        n0 = (idx & 31) * 32; k0 = (idx >> 5) * 32;
    } else if (idx < 5120) {                  // W1
        int i2 = idx - 1024; ib = W1; ob = W1t; K = 1024; N = 4096;
        n0 = (i2 & 127) * 32; k0 = (i2 >> 7) * 32;
    } else if (idx < 9216) {                  // W2
        int i2 = idx - 5120; ib = W2; ob = W2t; K = 4096; N = 1024;
        n0 = (i2 & 31) * 32; k0 = (i2 >> 5) * 32;
    } else {                                  // Wq/Wk/Wv heads
        int i2 = idx - 9216; int z = i2 >> 6; int t2 = i2 & 63;
        int mat = z >> 4, zz = z & 15;
        ib = (mat == 0 ? Wq : (mat == 1 ? Wk : Wv)) + (size_t)zz * 65536;
        ob = Wqkvt + (size_t)mat * 1048576 + (size_t)zz * 65536;
        K = 1024; N = 64;
        n0 = (t2 & 1) * 32; k0 = (t2 >> 1) * 32;
    }
    int r = tid >> 3, c4 = (tid & 7) * 4;
    float4 v = *(const float4*)(ib + (size_t)(k0 + r) * N + n0 + c4);
    t[r][c4] = v.x; t[r][c4+1] = v.y; t[r][c4+2] = v.z; t[r][c4+3] = v.w;
    __syncthreads();
    int n = tid >> 3, kc = (tid & 7) * 4;
    ushort4 o;
    o.x = f2bf(t[kc+0][n]); o.y = f2bf(t[kc+1][n]);
    o.z = f2bf(t[kc+2][n]); o.w = f2bf(t[kc+3][n]);
    *(ushort4*)(ob + (size_t)(n0 + n) * K + k0 + kc) = o;
}

// ---------------------------------------------------------------------------
// WIDE 128(M)x256(N) NT GEMM, bf16 MFMA, BK=32, 256 thr (4 waves of 64x128).
// 2-phase dbuf, 48KB LDS. 2D-rect XCD swizzle. Split-K via blockIdx.z.
// ---------------------------------------------------------------------------
template<int OUT_BF16>
__global__ __launch_bounds__(256, 2) void gemm_ntw_kernel(
    const ushort* __restrict__ A, int lda,
    const ushort* __restrict__ Bt, int ldb,
    void* __restrict__ C, int ldc, int K,
    const float* __restrict__ bias,
    const float* __restrict__ resid, int relu,
    long aZoff, long bZoff, long cZoff)
{
    __shared__ __attribute__((aligned(16))) ushort As[2][4][128][8];
    __shared__ __attribute__((aligned(16))) ushort Bs[2][4][256][8];

    A  += (size_t)blockIdx.z * aZoff;
    Bt += (size_t)blockIdx.z * bZoff;
    char* Cb = (char*)C + (size_t)blockIdx.z * cZoff * (OUT_BF16 ? 2 : 4);

    int bx, by;
    xcd_rect(gridDim.x, gridDim.y, &bx, &by);

    int row0 = by * 128, col0 = bx * 256;
    int tid = threadIdx.x;
    int w = tid >> 6, l = tid & 63;
    int wr = (w >> 1) * 64, wc = (w & 1) * 128;

    int m0 = tid & 127, kc0 = tid >> 7;
    const ushort* gA = A  + (size_t)(row0 + m0) * lda + kc0 * 8;
    const ushort* gB = Bt + (size_t)(col0 + tid) * ldb;

    f32x4 acc[4][8];
    #pragma unroll
    for (int i = 0; i < 4; ++i)
        #pragma unroll
        for (int j = 0; j < 8; ++j) acc[i][j] = (f32x4){0.f, 0.f, 0.f, 0.f};

    const int NT = K >> 5;
    g2l16(gA,      &As[0][kc0    ][m0][0]);
    g2l16(gA + 16, &As[0][kc0 + 2][m0][0]);
    #pragma unroll
    for (int p = 0; p < 4; ++p)
        g2l16(gB + p*8, &Bs[0][p][tid][0]);
    __syncthreads();

    int cur = 0;
    for (int t = 0; t < NT; ++t) {
        if (t + 1 < NT) {
            int k0 = (t + 1) << 5;
            g2l16(gA + k0,      &As[cur ^ 1][kc0    ][m0][0]);
            g2l16(gA + k0 + 16, &As[cur ^ 1][kc0 + 2][m0][0]);
            #pragma unroll
            for (int p = 0; p < 4; ++p)
                g2l16(gB + k0 + p*8, &Bs[cur ^ 1][p][tid][0]);
        }
        int kc = l >> 4;
        bf16x8 bfr[8];
        #pragma unroll
        for (int j = 0; j < 8; ++j)
            bfr[j] = *(const bf16x8*)&Bs[cur][kc][wc + j*16 + (l & 15)][0];
        #pragma unroll
        for (int i = 0; i < 4; ++i) {
            bf16x8 a = *(const bf16x8*)&As[cur][kc][wr + i*16 + (l & 15)][0];
            #pragma unroll
            for (int j = 0; j < 8; ++j)
                acc[i][j] = __builtin_amdgcn_mfma_f32_16x16x32_bf16(
                    a, bfr[j], acc[i][j], 0, 0, 0);
        }
        __syncthreads();
        cur ^= 1;
    }

    #pragma unroll
    for (int i = 0; i < 4; ++i) {
        int rbase = row0 + wr + i*16 + (l >> 4) * 4;
        #pragma unroll
        for (int j = 0; j < 8; ++j) {
            int col = col0 + wc + j*16 + (l & 15);
            float bv = bias ? bias[col] : 0.f;
            #pragma unroll
            for (int r = 0; r < 4; ++r) {
                int row = rbase + r;
                float val = acc[i][j][r] + bv;
                if (resid) val += resid[(size_t)row * ldc + col];
                if (relu)  val = fmaxf(val, 0.f);
                if (OUT_BF16) ((ushort*)Cb)[(size_t)row * ldc + col] = f2bf(val);
                else          ((float*)Cb)[(size_t)row * ldc + col]  = val;
            }
        }
    }
}

// ---------------------------------------------------------------------------
// 128x128 NT GEMM, BK=32, 2-phase dbuf, 32KB LDS, 2D-rect XCD swizzle,
// split-K via blockIdx.z. (kept for Wo)
// ---------------------------------------------------------------------------
template<int OUT_BF16>
__global__ __launch_bounds__(256) void gemm_nt_kernel(
    const ushort* __restrict__ A, int lda,
    const ushort* __restrict__ Bt, int ldb,
    void* __restrict__ C, int ldc, int K,
    const float* __restrict__ bias,
    const float* __restrict__ resid, int relu,
    long aZoff, long bZoff, long cZoff)
{
    __shared__ __attribute__((aligned(16))) ushort As[2][4][128][8];
    __shared__ __attribute__((aligned(16))) ushort Bs[2][4][128][8];

    A  += (size_t)blockIdx.z * aZoff;
    Bt += (size_t)blockIdx.z * bZoff;
    char* Cb = (char*)C + (size_t)blockIdx.z * cZoff * (OUT_BF16 ? 2 : 4);

    int bx, by;
    xcd_rect(gridDim.x, gridDim.y, &bx, &by);

    int row0 = by * 128, col0 = bx * 128;
    int tid = threadIdx.x;
    int w = tid >> 6, l = tid & 63;
    int wr = (w >> 1) * 64, wc = (w & 1) * 64;

    int m0 = tid & 127, kc0 = tid >> 7;
    const ushort* ga0 = A  + (size_t)(row0 + m0) * lda + kc0 * 8;
    const ushort* gb0 = Bt + (size_t)(col0 + m0) * ldb + kc0 * 8;

    f32x4 acc[4][4];
    #pragma unroll
    for (int i = 0; i < 4; ++i)
        #pragma unroll
        for (int j = 0; j < 4; ++j) acc[i][j] = (f32x4){0.f, 0.f, 0.f, 0.f};

    const int NT = K >> 5;
    g2l16(ga0,      &As[0][kc0    ][m0][0]);
    g2l16(ga0 + 16, &As[0][kc0 + 2][m0][0]);
    g2l16(gb0,      &Bs[0][kc0    ][m0][0]);
    g2l16(gb0 + 16, &Bs[0][kc0 + 2][m0][0]);
    __syncthreads();

    int cur = 0;
    for (int t = 0; t < NT; ++t) {
        if (t + 1 < NT) {
            int k0 = (t + 1) << 5;
            g2l16(ga0 + k0,      &As[cur ^ 1][kc0    ][m0][0]);
            g2l16(ga0 + k0 + 16, &As[cur ^ 1][kc0 + 2][m0][0]);
            g2l16(gb0 + k0,      &Bs[cur ^ 1][kc0    ][m0][0]);
            g2l16(gb0 + k0 + 16, &Bs[cur ^ 1][kc0 + 2][m0][0]);
        }
        int kc = l >> 4;
        bf16x8 af[4], bfr[4];
        #pragma unroll
        for (int i = 0; i < 4; ++i)
            af[i] = *(const bf16x8*)&As[cur][kc][wr + i*16 + (l & 15)][0];
        #pragma unroll
        for (int j = 0; j < 4; ++j)
            bfr[j] = *(const bf16x8*)&Bs[cur][kc][wc + j*16 + (l & 15)][0];
        #pragma unroll
        for (int i = 0; i < 4; ++i)
            #pragma unroll
            for (int j = 0; j < 4; ++j)
                acc[i][j] = __builtin_amdgcn_mfma_f32_16x16x32_bf16(
                    af[i], bfr[j], acc[i][j], 0, 0, 0);
        __syncthreads();
        cur ^= 1;
    }

    #pragma unroll
    for (int i = 0; i < 4; ++i) {
        int rbase = row0 + wr + i*16 + (l >> 4) * 4;
        #pragma unroll
        for (int j = 0; j < 4; ++j) {
            int col = col0 + wc + j*16 + (l & 15);
            float bv = bias ? bias[col] : 0.f;
            #pragma unroll
            for (int r = 0; r < 4; ++r) {
                int row = rbase + r;
                float val = acc[i][j][r] + bv;
                if (resid) val += resid[(size_t)row * ldc + col];
                if (relu)  val = fmaxf(val, 0.f);
                if (OUT_BF16) ((ushort*)Cb)[(size_t)row * ldc + col] = f2bf(val);
                else          ((float*)Cb)[(size_t)row * ldc + col]  = val;
            }
        }
    }
}

// ---------------------------------------------------------------------------
// csum + vscale fused, Q-tile dbuf, bh-major XCD swizzle, hoisted K-frags.
// ---------------------------------------------------------------------------
__global__ __launch_bounds__(256) void csumv_kernel(
    const ushort* __restrict__ qkv, ushort* __restrict__ vt)
{
    int nwg  = gridDim.x * gridDim.y;
    int orig = blockIdx.y * gridDim.x + blockIdx.x;
    int work = (orig & 7) * (nwg >> 3) + (orig >> 3);
    int bx = work % gridDim.x;
    int bh = work / gridDim.x;
    int b = bh >> 4, h = bh & 15;
    int s0 = bx * 128;
    const ushort* qb = qkv + (size_t)b * T_ * 3072 + h * 64;
    const ushort* kb = qb + 1024;
    const ushort* vb = qb + 2048;
    __shared__ __attribute__((aligned(16))) ushort Ks[8][128][8];
    __shared__ __attribute__((aligned(16))) ushort Qs[2][8][64][8];
    __shared__ float csl[128];
    __shared__ float t[64][65];
    int tid = threadIdx.x, w = tid >> 6, l = tid & 63;
    int scol = w * 32;
    int qq0 = l, kcA = w, kcB = w + 4;

    #pragma unroll
    for (int p = 0; p < 4; ++p) {
        int idx = tid + p * 256;
        int s = idx & 127, kc = idx >> 7;
        *(uint4*)&Ks[kc][s][0] =
            *(const uint4*)(kb + (size_t)(s0 + s) * 3072 + kc * 8);
    }
    g2l16(qb + (size_t)qq0 * 3072 + kcA * 8, &Qs[0][kcA][qq0][0]);
    g2l16(qb + (size_t)qq0 * 3072 + kcB * 8, &Qs[0][kcB][qq0][0]);
    __syncthreads();

    bf16x8 bfr[2][2];
    #pragma unroll
    for (int sj = 0; sj < 2; ++sj)
        #pragma unroll
        for (int ks = 0; ks < 2; ++ks)
            bfr[sj][ks] = *(const bf16x8*)&Ks[ks*4 + (l>>4)][scol + sj*16 + (l & 15)][0];

    float cs[2] = {0.f, 0.f};
    int cur = 0;
    for (int qt = 0; qt < T_ / 64; ++qt) {
        if (qt + 1 < T_ / 64) {
            const ushort* qn = qb + (size_t)((qt + 1) * 64 + qq0) * 3072;
            g2l16(qn + kcA * 8, &Qs[cur ^ 1][kcA][qq0][0]);
            g2l16(qn + kcB * 8, &Qs[cur ^ 1][kcB][qq0][0]);
        }
        bf16x8 af[4][2];
        #pragma unroll
        for (int qi = 0; qi < 4; ++qi)
            #pragma unroll
            for (int ks = 0; ks < 2; ++ks)
                af[qi][ks] = *(const bf16x8*)&Qs[cur][ks*4 + (l>>4)][qi*16 + (l & 15)][0];
        #pragma unroll
        for (int qi = 0; qi < 4; ++qi)
            #pragma unroll
            for (int sj = 0; sj < 2; ++sj) {
                f32x4 d = (f32x4){0.f, 0.f, 0.f, 0.f};
                #pragma unroll
                for (int ks = 0; ks < 2; ++ks)
                    d = __builtin_amdgcn_mfma_f32_16x16x32_bf16(
                        af[qi][ks], bfr[sj][ks], d, 0, 0, 0);
                cs[sj] += __expf(d[0]*0.125f) + __expf(d[1]*0.125f)
                        + __expf(d[2]*0.125f) + __expf(d[3]*0.125f);
            }
        __syncthreads();
        cur ^= 1;
    }
    #pragma unroll
    for (int sj = 0; sj < 2; ++sj) {
        float v = cs[sj];
        v += __shfl_down(v, 32, 64);
        v += __shfl_down(v, 16, 64);
        if (l < 16) csl[scol + sj*16 + l] = v;
    }
    __syncthreads();

    #pragma unroll
    for (int p2 = 0; p2 < 2; ++p2) {
        int sb = s0 + p2 * 64;
        #pragma unroll
        for (int p = 0; p < 2; ++p) {
            int idx = tid + p * 256;
            int s = idx >> 3, c0 = (idx & 7) * 8;
            uint4 raw = *(const uint4*)(vb + (size_t)(sb + s) * 3072 + c0);
            float rc = 1.0f / csl[p2 * 64 + s];
            ushort* u = (ushort*)&raw;
            #pragma unroll
            for (int i = 0; i < 8; ++i) t[s][c0 + i] = bf2f(u[i]) * rc;
        }
        __syncthreads();
        #pragma unroll
        for (int p = 0; p < 2; ++p) {
            int idx = tid + p * 256;
            int dv = idx >> 3, sc = (idx & 7) * 8;
            ushort o[8];
            #pragma unroll
            for (int i = 0; i < 8; ++i) o[i] = f2bf(t[sc + i][dv]);
            *(uint4*)(vt + ((size_t)bh * 64 + dv) * T_ + sb + sc) = *(uint4*)o;
        }
        __syncthreads();
    }
}

// ---------------------------------------------------------------------------
// PV: QBLK=128, K/V dbuf, Q in regs, bh-major XCD swizzle, swapped-QK^T
// packed-E.
// ---------------------------------------------------------------------------
__global__ __launch_bounds__(256) void attn_pv_kernel(
    const ushort* __restrict__ qkv, const ushort* __restrict__ vt,
    ushort* __restrict__ attn_o)
{
    int nwg  = gridDim.x * gridDim.y;
    int orig = blockIdx.y * gridDim.x + blockIdx.x;
    int work = (orig & 7) * (nwg >> 3) + (orig >> 3);
    int bx = work % gridDim.x;
    int bh = work / gridDim.x;
    int b = bh >> 4, h = bh & 15;
    int q0 = bx * 128;
    const ushort* qb = qkv + (size_t)b * T_ * 3072 + h * 64;
    const ushort* kb = qb + 1024;
    const ushort* vtb = vt + (size_t)bh * 64 * T_;
    __shared__ __attribute__((aligned(16))) ushort Ks[2][8][64][8];
    __shared__ __attribute__((aligned(16))) ushort Vs[2][8][64][8];
    __shared__ __attribute__((aligned(16))) ushort Es[128][64]; // [q][s], swizzled
    int tid = threadIdx.x, w = tid >> 6, l = tid & 63;
    int wq = w * 32;
    int kcA = w, kcB = w + 4;

    bf16x8 qf[2][2];
    #pragma unroll
    for (int qt = 0; qt < 2; ++qt)
        #pragma unroll
        for (int ks = 0; ks < 2; ++ks)
            qf[qt][ks] = *(const bf16x8*)(qb
                + (size_t)(q0 + wq + qt*16 + (l & 15)) * 3072
                + (ks*4 + (l >> 4)) * 8);

    f32x4 oacc[2][4];
    #pragma unroll
    for (int qt = 0; qt < 2; ++qt)
        #pragma unroll
        for (int j = 0; j < 4; ++j) oacc[qt][j] = (f32x4){0.f, 0.f, 0.f, 0.f};

    const int NT = T_ / 64;
    g2l16(kb + (size_t)l * 3072 + kcA * 8, &Ks[0][kcA][l][0]);
    g2l16(kb + (size_t)l * 3072 + kcB * 8, &Ks[0][kcB][l][0]);
    g2l16(vtb + (size_t)l * T_ + kcA * 8,  &Vs[0][kcA][l][0]);
    g2l16(vtb + (size_t)l * T_ + kcB * 8,  &Vs[0][kcB][l][0]);
    __syncthreads();

    int cur = 0;
    for (int st = 0; st < NT; ++st) {
        if (st + 1 < NT) {
            int s1 = (st + 1) * 64;
            g2l16(kb + (size_t)(s1 + l) * 3072 + kcA * 8, &Ks[cur^1][kcA][l][0]);
            g2l16(kb + (size_t)(s1 + l) * 3072 + kcB * 8, &Ks[cur^1][kcB][l][0]);
            g2l16(vtb + (size_t)l * T_ + s1 + kcA * 8,    &Vs[cur^1][kcA][l][0]);
            g2l16(vtb + (size_t)l * T_ + s1 + kcB * 8,    &Vs[cur^1][kcB][l][0]);
        }
        #pragma unroll
        for (int sj = 0; sj < 4; ++sj) {
            bf16x8 kfa[2];
            #pragma unroll
            for (int ks = 0; ks < 2; ++ks)
                kfa[ks] = *(const bf16x8*)&Ks[cur][ks*4 + (l>>4)][sj*16 + (l & 15)][0];
            #pragma unroll
            for (int qt = 0; qt < 2; ++qt) {
                f32x4 d = (f32x4){0.f, 0.f, 0.f, 0.f};
                #pragma unroll
                for (int ks = 0; ks < 2; ++ks)
                    d = __builtin_amdgcn_mfma_f32_16x16x32_bf16(
                        kfa[ks], qf[qt][ks], d, 0, 0, 0);
                int row = wq + qt*16 + (l & 15);
                int c16 = sj*2 + ((l >> 4) >> 1);
                int sub = (l >> 4) & 1;
                uint2 pv2;
                pv2.x = pk2(__expf(d[0]*0.125f), __expf(d[1]*0.125f));
                pv2.y = pk2(__expf(d[2]*0.125f), __expf(d[3]*0.125f));
                *(uint2*)((char*)Es + row*128 + ((c16 ^ (row & 7))*16 + sub*8)) = pv2;
            }
        }
        bf16x8 efa[2][2];
        #pragma unroll
        for (int qt = 0; qt < 2; ++qt) {
            int row = wq + qt*16 + (l & 15);
            #pragma unroll
            for (int ks = 0; ks < 2; ++ks)
                efa[qt][ks] = *(const bf16x8*)((char*)Es + row*128
                    + (((ks*4 + (l >> 4)) ^ (row & 7))*16));
        }
        #pragma unroll
        for (int j = 0; j < 4; ++j)
            #pragma unroll
            for (int ks = 0; ks < 2; ++ks) {
                bf16x8 vf = *(const bf16x8*)&Vs[cur][ks*4 + (l>>4)][j*16 + (l & 15)][0];
                #pragma unroll
                for (int qt = 0; qt < 2; ++qt)
                    oacc[qt][j] = __builtin_amdgcn_mfma_f32_16x16x32_bf16(
                        efa[qt][ks], vf, oacc[qt][j], 0, 0, 0);
            }
        __syncthreads();
        cur ^= 1;
    }

    #pragma unroll
    for (int qt = 0; qt < 2; ++qt)
        #pragma unroll
        for (int j = 0; j < 4; ++j)
            #pragma unroll
            for (int r = 0; r < 4; ++r) {
                int qq = q0 + wq + qt*16 + (l>>4)*4 + r;
                int dv = j*16 + (l & 15);
                attn_o[(size_t)(b*T_ + qq) * 1024 + h*64 + dv] = f2bf(oacc[qt][j][r]);
            }
}

// ---------------------------------------------------------------------------
// fused norm
// ---------------------------------------------------------------------------
__device__ __forceinline__ float block_reduce_sum_256(float v, float* tmp)
{
    #pragma unroll
    for (int off = 32; off; off >>= 1) v += __shfl_down(v, off, 64);
    int lane = threadIdx.x & 63, w = threadIdx.x >> 6;
    __syncthreads();
    if (lane == 0) tmp[w] = v;
    __syncthreads();
    return tmp[0] + tmp[1] + tmp[2] + tmp[3];
}

template<int Z>
__global__ __launch_bounds__(256) void normZ_fused_kernel(
    const ushort* __restrict__ parts, long zoff,
    const float* __restrict__ bias, const float* __restrict__ resid,
    float* __restrict__ outf, ushort* __restrict__ outb)
{
    __shared__ float tmp[4];
    int row = blockIdx.x;
    int tid = threadIdx.x;
    int c0 = tid * 4;
    size_t idx = (size_t)row * D_ + c0;
    float vals[4] = {0.f, 0.f, 0.f, 0.f};
    #pragma unroll
    for (int z = 0; z < Z; ++z) {
        ushort4 p = *(const ushort4*)&parts[idx + (size_t)z * zoff];
        vals[0] += bf2f(p.x); vals[1] += bf2f(p.y);
        vals[2] += bf2f(p.z); vals[3] += bf2f(p.w);
    }
    float4 rv = *(const float4*)&resid[idx];
    vals[0] += rv.x; vals[1] += rv.y; vals[2] += rv.z; vals[3] += rv.w;
    if (bias) {
        float4 bv = *(const float4*)&bias[c0];
        vals[0] += bv.x; vals[1] += bv.y; vals[2] += bv.z; vals[3] += bv.w;
    }
    float s = vals[0] + vals[1] + vals[2] + vals[3];
    s = block_reduce_sum_256(s, tmp);
    float m = s * (1.0f / (float)D_);
    float sq = 0.f;
    #pragma unroll
    for (int i = 0; i < 4; ++i) { float c = vals[i] - m; sq += c * c; }
    sq = block_reduce_sum_256(sq, tmp);
    float rs = rsqrtf(sq * (1.0f / (float)(D_ - 1)));
    float4 o;
    o.x = (vals[0] - m) * rs; o.y = (vals[1] - m) * rs;
    o.z = (vals[2] - m) * rs; o.w = (vals[3] - m) * rs;
    *(float4*)&outf[idx] = o;
    if (outb) {
        ushort4 ob;
        ob.x = f2bf(o.x); ob.y = f2bf(o.y); ob.z = f2bf(o.z); ob.w = f2bf(o.w);
        *(ushort4*)&outb[idx] = ob;
    }
}

// ---------------------------------------------------------------------------
extern "C" void kernel_launch(void* const* d_in, const int* in_sizes, int n_in,
                              void* d_out, int out_size, void* d_ws, size_t ws_size,
                              hipStream_t stream)
{
    const float* x  = (const float*)d_in[0];
    const float* Wq = (const float*)d_in[1];
    const float* Wk = (const float*)d_in[2];
    const float* Wv = (const float*)d_in[3];
    const float* Wo = (const float*)d_in[4];
    const float* W1 = (const float*)d_in[5];
    const float* b1 = (const float*)d_in[6];
    const float* W2 = (const float*)d_in[7];
    const float* b2 = (const float*)d_in[8];
    float* out = (float*)d_out;

    const size_t MB = (size_t)1 << 20;
    char* base = (char*)d_ws;
    ushort* qkv    = (ushort*)(base +   0*MB);  // 24MB  [QKV..PV]
    ushort* hid    = (ushort*)(base +   0*MB);  // 32MB  [W1..W2]
    ushort* xb     = (ushort*)(base +  24*MB);  //  8MB  [prep..QKV]
    ushort* W2t    = (ushort*)(base +  32*MB);  //  8MB  [prep..W2]
    ushort* Wqkvt  = (ushort*)(base +  40*MB);  //  6MB  [prep..QKV]
    ushort* wpart  = (ushort*)(base +  40*MB);  // 32MB  [W2..norm2]
    ushort* vt     = (ushort*)(base +  46*MB);  //  8MB  [csumv..PV]
    ushort* Wot    = (ushort*)(base +  55*MB);  //  2MB  [prep..Wo]
    ushort* W1t    = (ushort*)(base +  57*MB);  //  8MB  [prep..W1]
    ushort* attn_o = (ushort*)(base +  65*MB);  //  8MB  [PV..Wo]
    ushort* wopart = (ushort*)(base +  73*MB);  // 16MB  [Wo..norm1]
    ushort* out1b  = (ushort*)(base +  89*MB);  //  8MB  [norm1..W1]
    float*  out1f  = (float*) (base +  97*MB);  // 16MB  [norm1..norm2]

    // 1. single fused prep: all converts + transposes
    prep_kernel<<<dim3(14336), 256, 0, stream>>>(
        x, Wq, Wk, Wv, Wo, W1, W2, xb, Wqkvt, Wot, W1t, W2t);

    // 2. QKV: wide tile, 384 blocks.
    gemm_ntw_kernel<1><<<dim3(3072/256, 4096/128, 1), 256, 0, stream>>>(
        xb, 1024, Wqkvt, 1024, qkv, 3072, 1024, nullptr, nullptr, 0, 0, 0, 0);
    // 3. colsum + V-scale/transpose fused
    csumv_kernel<<<dim3(T_/128, B_*H_), 256, 0, stream>>>(qkv, vt);
    // 4. PV
    attn_pv_kernel<<<dim3(T_/128, B_*H_), 256, 0, stream>>>(qkv, vt, attn_o);
    // 5. Wo split-K2 -> bf16 partials. 512 blocks.
    gemm_nt_kernel<1><<<dim3(1024/128, 4096/128, 2), 256, 0, stream>>>(
        attn_o, 1024, Wot, 1024, wopart, 1024, 512, nullptr, nullptr, 0,
        512, 512, (long)4096*1024);
    // 6. norm1 fused
    normZ_fused_kernel<2><<<dim3(BT_), 256, 0, stream>>>(
        wopart, (long)4096*1024, nullptr, x, out1f, out1b);
    // 7. FFN up + ReLU: wide tile, 512 blocks.
    gemm_ntw_kernel<1><<<dim3(4096/256, 4096/128, 1), 256, 0, stream>>>(
        out1b, 1024, W1t, 1024, hid, 4096, 1024, b1, nullptr, 1, 0, 0, 0);
    // 8. FFN down: wide tile + split-K4. 512 blocks.
    gemm_ntw_kernel<1><<<dim3(1024/256, 4096/128, 4), 256, 0, stream>>>(
        hid, 4096, W2t, 4096, wpart, 1024, 1024, nullptr, nullptr, 0,
        1024, 1024, (long)4096*1024);
    // 9. norm2 fused: sum 4 partials + b2 + out1 resid -> out
    normZ_fused_kernel<4><<<dim3(BT_), 256, 0, stream>>>(
        wpart, (long)4096*1024, b2, out1f, out, nullptr);
}

// Round 18
// 354.666 us; speedup vs baseline: 1.0372x; 1.0096x over previous
//
#include <hip/hip_runtime.h>
#include <hip/hip_bf16.h>
#include <math.h>

#define B_  2
#define T_  2048
#define D_  1024
#define H_  16
#define DK_ 64
#define FF_ 4096
#define BT_ (B_*T_)

typedef __attribute__((ext_vector_type(8))) short bf16x8;
typedef __attribute__((ext_vector_type(4))) float f32x4;

__device__ __forceinline__ ushort f2bf(float f) {
    __hip_bfloat16 h = __float2bfloat16(f);
    return *reinterpret_cast<ushort*>(&h);
}
__device__ __forceinline__ float bf2f(ushort u) {
    __hip_bfloat16 h;
    *reinterpret_cast<ushort*>(&h) = u;
    return __bfloat162float(h);
}
__device__ __forceinline__ uint pk2(float a, float b) {
    return (uint)f2bf(a) | ((uint)f2bf(b) << 16);
}

// async global->LDS, 16B per lane. LDS dest must be wave-uniform base + lane*16.
__device__ __forceinline__ void g2l16(const ushort* g, ushort* l) {
    __builtin_amdgcn_global_load_lds(
        (const __attribute__((address_space(1))) void*)g,
        (__attribute__((address_space(3))) void*)l, 16, 0, 0);
}

// 2D-rect XCD swizzle (kept from R17: neutral but not harmful).
__device__ __forceinline__ void xcd_rect(int gx, int gy, int* bx, int* by) {
    int orig = blockIdx.y * gx + blockIdx.x;
    int xg = (gx & 1) ? 1 : 2;
    int rw = gx / xg, rh = (gy * xg) >> 3;
    int xcd = orig & 7, i = orig >> 3;
    *bx = (xcd % xg) * rw + i % rw;
    *by = (xcd / xg) * rh + i / rw;
}

// ---------------------------------------------------------------------------
// prep: ONE kernel for all input conversions/transposes.
// ---------------------------------------------------------------------------
__global__ __launch_bounds__(256) void prep_kernel(
    const float* __restrict__ x,
    const float* __restrict__ Wq, const float* __restrict__ Wk,
    const float* __restrict__ Wv, const float* __restrict__ Wo,
    const float* __restrict__ W1, const float* __restrict__ W2,
    ushort* __restrict__ xb, ushort* __restrict__ Wqkvt,
    ushort* __restrict__ Wot, ushort* __restrict__ W1t,
    ushort* __restrict__ W2t)
{
    int idx = blockIdx.x;
    int tid = threadIdx.x;
    if (idx >= 12288) {                       // x convert, 2048/block
        int i = (idx - 12288) * 2048 + tid * 4;
        #pragma unroll
        for (int p = 0; p < 2; ++p) {
            float4 v = *(const float4*)(x + i + p * 1024);
            ushort4 o;
            o.x = f2bf(v.x); o.y = f2bf(v.y); o.z = f2bf(v.z); o.w = f2bf(v.w);
            *(ushort4*)(xb + i + p * 1024) = o;
        }
        return;
    }
    __shared__ float t[32][33];
    const float* ib; ushort* ob; int K, N, n0, k0;
    if (idx < 1024) {                         // Wo
        ib = Wo; ob = Wot; K = 1024; N = 1024;
        n0 = (idx & 31) * 32; k0 = (idx >> 5) * 32;
    } else if (idx < 5120) {                  // W1
        int i2 = idx - 1024; ib = W1; ob = W1t; K = 1024; N = 4096;
        n0 = (i2 & 127) * 32; k0 = (i2 >> 7) * 32;
    } else if (idx < 9216) {                  // W2
        int i2 = idx - 5120; ib = W2; ob = W2t; K = 4096; N = 1024;
        n0 = (i2 & 31) * 32; k0 = (i2 >> 5) * 32;
    } else {                                  // Wq/Wk/Wv heads
        int i2 = idx - 9216; int z = i2 >> 6; int t2 = i2 & 63;
        int mat = z >> 4, zz = z & 15;
        ib = (mat == 0 ? Wq : (mat == 1 ? Wk : Wv)) + (size_t)zz * 65536;
        ob = Wqkvt + (size_t)mat * 1048576 + (size_t)zz * 65536;
        K = 1024; N = 64;
        n0 = (t2 & 1) * 32; k0 = (t2 >> 1) * 32;
    }
    int r = tid >> 3, c4 = (tid & 7) * 4;
    float4 v = *(const float4*)(ib + (size_t)(k0 + r) * N + n0 + c4);
    t[r][c4] = v.x; t[r][c4+1] = v.y; t[r][c4+2] = v.z; t[r][c4+3] = v.w;
    __syncthreads();
    int n = tid >> 3, kc = (tid & 7) * 4;
    ushort4 o;
    o.x = f2bf(t[kc+0][n]); o.y = f2bf(t[kc+1][n]);
    o.z = f2bf(t[kc+2][n]); o.w = f2bf(t[kc+3][n]);
    *(ushort4*)(ob + (size_t)(n0 + n) * K + k0 + kc) = o;
}

// ---------------------------------------------------------------------------
// WIDE 128(M)x256(N) NT GEMM, bf16 MFMA, BK=32, 2-phase dbuf, 48KB LDS.
// ---------------------------------------------------------------------------
template<int OUT_BF16>
__global__ __launch_bounds__(256, 2) void gemm_ntw_kernel(
    const ushort* __restrict__ A, int lda,
    const ushort* __restrict__ Bt, int ldb,
    void* __restrict__ C, int ldc, int K,
    const float* __restrict__ bias,
    const float* __restrict__ resid, int relu,
    long aZoff, long bZoff, long cZoff)
{
    __shared__ __attribute__((aligned(16))) ushort As[2][4][128][8];
    __shared__ __attribute__((aligned(16))) ushort Bs[2][4][256][8];

    A  += (size_t)blockIdx.z * aZoff;
    Bt += (size_t)blockIdx.z * bZoff;
    char* Cb = (char*)C + (size_t)blockIdx.z * cZoff * (OUT_BF16 ? 2 : 4);

    int bx, by;
    xcd_rect(gridDim.x, gridDim.y, &bx, &by);

    int row0 = by * 128, col0 = bx * 256;
    int tid = threadIdx.x;
    int w = tid >> 6, l = tid & 63;
    int wr = (w >> 1) * 64, wc = (w & 1) * 128;

    int m0 = tid & 127, kc0 = tid >> 7;
    const ushort* gA = A  + (size_t)(row0 + m0) * lda + kc0 * 8;
    const ushort* gB = Bt + (size_t)(col0 + tid) * ldb;

    f32x4 acc[4][8];
    #pragma unroll
    for (int i = 0; i < 4; ++i)
        #pragma unroll
        for (int j = 0; j < 8; ++j) acc[i][j] = (f32x4){0.f, 0.f, 0.f, 0.f};

    const int NT = K >> 5;
    g2l16(gA,      &As[0][kc0    ][m0][0]);
    g2l16(gA + 16, &As[0][kc0 + 2][m0][0]);
    #pragma unroll
    for (int p = 0; p < 4; ++p)
        g2l16(gB + p*8, &Bs[0][p][tid][0]);
    __syncthreads();

    int cur = 0;
    for (int t = 0; t < NT; ++t) {
        if (t + 1 < NT) {
            int k0 = (t + 1) << 5;
            g2l16(gA + k0,      &As[cur ^ 1][kc0    ][m0][0]);
            g2l16(gA + k0 + 16, &As[cur ^ 1][kc0 + 2][m0][0]);
            #pragma unroll
            for (int p = 0; p < 4; ++p)
                g2l16(gB + k0 + p*8, &Bs[cur ^ 1][p][tid][0]);
        }
        int kc = l >> 4;
        bf16x8 bfr[8];
        #pragma unroll
        for (int j = 0; j < 8; ++j)
            bfr[j] = *(const bf16x8*)&Bs[cur][kc][wc + j*16 + (l & 15)][0];
        #pragma unroll
        for (int i = 0; i < 4; ++i) {
            bf16x8 a = *(const bf16x8*)&As[cur][kc][wr + i*16 + (l & 15)][0];
            #pragma unroll
            for (int j = 0; j < 8; ++j)
                acc[i][j] = __builtin_amdgcn_mfma_f32_16x16x32_bf16(
                    a, bfr[j], acc[i][j], 0, 0, 0);
        }
        __syncthreads();
        cur ^= 1;
    }

    #pragma unroll
    for (int i = 0; i < 4; ++i) {
        int rbase = row0 + wr + i*16 + (l >> 4) * 4;
        #pragma unroll
        for (int j = 0; j < 8; ++j) {
            int col = col0 + wc + j*16 + (l & 15);
            float bv = bias ? bias[col] : 0.f;
            #pragma unroll
            for (int r = 0; r < 4; ++r) {
                int row = rbase + r;
                float val = acc[i][j][r] + bv;
                if (resid) val += resid[(size_t)row * ldc + col];
                if (relu)  val = fmaxf(val, 0.f);
                if (OUT_BF16) ((ushort*)Cb)[(size_t)row * ldc + col] = f2bf(val);
                else          ((float*)Cb)[(size_t)row * ldc + col]  = val;
            }
        }
    }
}

// ---------------------------------------------------------------------------
// 128x128 NT GEMM, BK=32, 2-phase dbuf, 32KB LDS (kept for Wo).
// ---------------------------------------------------------------------------
template<int OUT_BF16>
__global__ __launch_bounds__(256) void gemm_nt_kernel(
    const ushort* __restrict__ A, int lda,
    const ushort* __restrict__ Bt, int ldb,
    void* __restrict__ C, int ldc, int K,
    const float* __restrict__ bias,
    const float* __restrict__ resid, int relu,
    long aZoff, long bZoff, long cZoff)
{
    __shared__ __attribute__((aligned(16))) ushort As[2][4][128][8];
    __shared__ __attribute__((aligned(16))) ushort Bs[2][4][128][8];

    A  += (size_t)blockIdx.z * aZoff;
    Bt += (size_t)blockIdx.z * bZoff;
    char* Cb = (char*)C + (size_t)blockIdx.z * cZoff * (OUT_BF16 ? 2 : 4);

    int bx, by;
    xcd_rect(gridDim.x, gridDim.y, &bx, &by);

    int row0 = by * 128, col0 = bx * 128;
    int tid = threadIdx.x;
    int w = tid >> 6, l = tid & 63;
    int wr = (w >> 1) * 64, wc = (w & 1) * 64;

    int m0 = tid & 127, kc0 = tid >> 7;
    const ushort* ga0 = A  + (size_t)(row0 + m0) * lda + kc0 * 8;
    const ushort* gb0 = Bt + (size_t)(col0 + m0) * ldb + kc0 * 8;

    f32x4 acc[4][4];
    #pragma unroll
    for (int i = 0; i < 4; ++i)
        #pragma unroll
        for (int j = 0; j < 4; ++j) acc[i][j] = (f32x4){0.f, 0.f, 0.f, 0.f};

    const int NT = K >> 5;
    g2l16(ga0,      &As[0][kc0    ][m0][0]);
    g2l16(ga0 + 16, &As[0][kc0 + 2][m0][0]);
    g2l16(gb0,      &Bs[0][kc0    ][m0][0]);
    g2l16(gb0 + 16, &Bs[0][kc0 + 2][m0][0]);
    __syncthreads();

    int cur = 0;
    for (int t = 0; t < NT; ++t) {
        if (t + 1 < NT) {
            int k0 = (t + 1) << 5;
            g2l16(ga0 + k0,      &As[cur ^ 1][kc0    ][m0][0]);
            g2l16(ga0 + k0 + 16, &As[cur ^ 1][kc0 + 2][m0][0]);
            g2l16(gb0 + k0,      &Bs[cur ^ 1][kc0    ][m0][0]);
            g2l16(gb0 + k0 + 16, &Bs[cur ^ 1][kc0 + 2][m0][0]);
        }
        int kc = l >> 4;
        bf16x8 af[4], bfr[4];
        #pragma unroll
        for (int i = 0; i < 4; ++i)
            af[i] = *(const bf16x8*)&As[cur][kc][wr + i*16 + (l & 15)][0];
        #pragma unroll
        for (int j = 0; j < 4; ++j)
            bfr[j] = *(const bf16x8*)&Bs[cur][kc][wc + j*16 + (l & 15)][0];
        #pragma unroll
        for (int i = 0; i < 4; ++i)
            #pragma unroll
            for (int j = 0; j < 4; ++j)
                acc[i][j] = __builtin_amdgcn_mfma_f32_16x16x32_bf16(
                    af[i], bfr[j], acc[i][j], 0, 0, 0);
        __syncthreads();
        cur ^= 1;
    }

    #pragma unroll
    for (int i = 0; i < 4; ++i) {
        int rbase = row0 + wr + i*16 + (l >> 4) * 4;
        #pragma unroll
        for (int j = 0; j < 4; ++j) {
            int col = col0 + wc + j*16 + (l & 15);
            float bv = bias ? bias[col] : 0.f;
            #pragma unroll
            for (int r = 0; r < 4; ++r) {
                int row = rbase + r;
                float val = acc[i][j][r] + bv;
                if (resid) val += resid[(size_t)row * ldc + col];
                if (relu)  val = fmaxf(val, 0.f);
                if (OUT_BF16) ((ushort*)Cb)[(size_t)row * ldc + col] = f2bf(val);
                else          ((float*)Cb)[(size_t)row * ldc + col]  = val;
            }
        }
    }
}

// ---------------------------------------------------------------------------
// csum + vscale fused, Q-tile dbuf, bh-major XCD swizzle, hoisted K-frags.
// ---------------------------------------------------------------------------
__global__ __launch_bounds__(256) void csumv_kernel(
    const ushort* __restrict__ qkv, ushort* __restrict__ vt)
{
    int nwg  = gridDim.x * gridDim.y;
    int orig = blockIdx.y * gridDim.x + blockIdx.x;
    int work = (orig & 7) * (nwg >> 3) + (orig >> 3);
    int bx = work % gridDim.x;
    int bh = work / gridDim.x;
    int b = bh >> 4, h = bh & 15;
    int s0 = bx * 128;
    const ushort* qb = qkv + (size_t)b * T_ * 3072 + h * 64;
    const ushort* kb = qb + 1024;
    const ushort* vb = qb + 2048;
    __shared__ __attribute__((aligned(16))) ushort Ks[8][128][8];
    __shared__ __attribute__((aligned(16))) ushort Qs[2][8][64][8];
    __shared__ float csl[128];
    __shared__ float t[64][65];
    int tid = threadIdx.x, w = tid >> 6, l = tid & 63;
    int scol = w * 32;
    int qq0 = l, kcA = w, kcB = w + 4;

    #pragma unroll
    for (int p = 0; p < 4; ++p) {
        int idx = tid + p * 256;
        int s = idx & 127, kc = idx >> 7;
        *(uint4*)&Ks[kc][s][0] =
            *(const uint4*)(kb + (size_t)(s0 + s) * 3072 + kc * 8);
    }
    g2l16(qb + (size_t)qq0 * 3072 + kcA * 8, &Qs[0][kcA][qq0][0]);
    g2l16(qb + (size_t)qq0 * 3072 + kcB * 8, &Qs[0][kcB][qq0][0]);
    __syncthreads();

    bf16x8 bfr[2][2];
    #pragma unroll
    for (int sj = 0; sj < 2; ++sj)
        #pragma unroll
        for (int ks = 0; ks < 2; ++ks)
            bfr[sj][ks] = *(const bf16x8*)&Ks[ks*4 + (l>>4)][scol + sj*16 + (l & 15)][0];

    float cs[2] = {0.f, 0.f};
    int cur = 0;
    for (int qt = 0; qt < T_ / 64; ++qt) {
        if (qt + 1 < T_ / 64) {
            const ushort* qn = qb + (size_t)((qt + 1) * 64 + qq0) * 3072;
            g2l16(qn + kcA * 8, &Qs[cur ^ 1][kcA][qq0][0]);
            g2l16(qn + kcB * 8, &Qs[cur ^ 1][kcB][qq0][0]);
        }
        bf16x8 af[4][2];
        #pragma unroll
        for (int qi = 0; qi < 4; ++qi)
            #pragma unroll
            for (int ks = 0; ks < 2; ++ks)
                af[qi][ks] = *(const bf16x8*)&Qs[cur][ks*4 + (l>>4)][qi*16 + (l & 15)][0];
        #pragma unroll
        for (int qi = 0; qi < 4; ++qi)
            #pragma unroll
            for (int sj = 0; sj < 2; ++sj) {
                f32x4 d = (f32x4){0.f, 0.f, 0.f, 0.f};
                #pragma unroll
                for (int ks = 0; ks < 2; ++ks)
                    d = __builtin_amdgcn_mfma_f32_16x16x32_bf16(
                        af[qi][ks], bfr[sj][ks], d, 0, 0, 0);
                cs[sj] += __expf(d[0]*0.125f) + __expf(d[1]*0.125f)
                        + __expf(d[2]*0.125f) + __expf(d[3]*0.125f);
            }
        __syncthreads();
        cur ^= 1;
    }
    #pragma unroll
    for (int sj = 0; sj < 2; ++sj) {
        float v = cs[sj];
        v += __shfl_down(v, 32, 64);
        v += __shfl_down(v, 16, 64);
        if (l < 16) csl[scol + sj*16 + l] = v;
    }
    __syncthreads();

    #pragma unroll
    for (int p2 = 0; p2 < 2; ++p2) {
        int sb = s0 + p2 * 64;
        #pragma unroll
        for (int p = 0; p < 2; ++p) {
            int idx = tid + p * 256;
            int s = idx >> 3, c0 = (idx & 7) * 8;
            uint4 raw = *(const uint4*)(vb + (size_t)(sb + s) * 3072 + c0);
            float rc = 1.0f / csl[p2 * 64 + s];
            ushort* u = (ushort*)&raw;
            #pragma unroll
            for (int i = 0; i < 8; ++i) t[s][c0 + i] = bf2f(u[i]) * rc;
        }
        __syncthreads();
        #pragma unroll
        for (int p = 0; p < 2; ++p) {
            int idx = tid + p * 256;
            int dv = idx >> 3, sc = (idx & 7) * 8;
            ushort o[8];
            #pragma unroll
            for (int i = 0; i < 8; ++i) o[i] = f2bf(t[sc + i][dv]);
            *(uint4*)(vt + ((size_t)bh * 64 + dv) * T_ + sb + sc) = *(uint4*)o;
        }
        __syncthreads();
    }
}

// ---------------------------------------------------------------------------
// PV: QBLK=128, K/V dbuf, Q in regs, bh-major XCD swizzle, swapped-QK^T
// packed-E.
// ---------------------------------------------------------------------------
__global__ __launch_bounds__(256) void attn_pv_kernel(
    const ushort* __restrict__ qkv, const ushort* __restrict__ vt,
    ushort* __restrict__ attn_o)
{
    int nwg  = gridDim.x * gridDim.y;
    int orig = blockIdx.y * gridDim.x + blockIdx.x;
    int work = (orig & 7) * (nwg >> 3) + (orig >> 3);
    int bx = work % gridDim.x;
    int bh = work / gridDim.x;
    int b = bh >> 4, h = bh & 15;
    int q0 = bx * 128;
    const ushort* qb = qkv + (size_t)b * T_ * 3072 + h * 64;
    const ushort* kb = qb + 1024;
    const ushort* vtb = vt + (size_t)bh * 64 * T_;
    __shared__ __attribute__((aligned(16))) ushort Ks[2][8][64][8];
    __shared__ __attribute__((aligned(16))) ushort Vs[2][8][64][8];
    __shared__ __attribute__((aligned(16))) ushort Es[128][64]; // [q][s], swizzled
    int tid = threadIdx.x, w = tid >> 6, l = tid & 63;
    int wq = w * 32;
    int kcA = w, kcB = w + 4;

    bf16x8 qf[2][2];
    #pragma unroll
    for (int qt = 0; qt < 2; ++qt)
        #pragma unroll
        for (int ks = 0; ks < 2; ++ks)
            qf[qt][ks] = *(const bf16x8*)(qb
                + (size_t)(q0 + wq + qt*16 + (l & 15)) * 3072
                + (ks*4 + (l >> 4)) * 8);

    f32x4 oacc[2][4];
    #pragma unroll
    for (int qt = 0; qt < 2; ++qt)
        #pragma unroll
        for (int j = 0; j < 4; ++j) oacc[qt][j] = (f32x4){0.f, 0.f, 0.f, 0.f};

    const int NT = T_ / 64;
    g2l16(kb + (size_t)l * 3072 + kcA * 8, &Ks[0][kcA][l][0]);
    g2l16(kb + (size_t)l * 3072 + kcB * 8, &Ks[0][kcB][l][0]);
    g2l16(vtb + (size_t)l * T_ + kcA * 8,  &Vs[0][kcA][l][0]);
    g2l16(vtb + (size_t)l * T_ + kcB * 8,  &Vs[0][kcB][l][0]);
    __syncthreads();

    int cur = 0;
    for (int st = 0; st < NT; ++st) {
        if (st + 1 < NT) {
            int s1 = (st + 1) * 64;
            g2l16(kb + (size_t)(s1 + l) * 3072 + kcA * 8, &Ks[cur^1][kcA][l][0]);
            g2l16(kb + (size_t)(s1 + l) * 3072 + kcB * 8, &Ks[cur^1][kcB][l][0]);
            g2l16(vtb + (size_t)l * T_ + s1 + kcA * 8,    &Vs[cur^1][kcA][l][0]);
            g2l16(vtb + (size_t)l * T_ + s1 + kcB * 8,    &Vs[cur^1][kcB][l][0]);
        }
        #pragma unroll
        for (int sj = 0; sj < 4; ++sj) {
            bf16x8 kfa[2];
            #pragma unroll
            for (int ks = 0; ks < 2; ++ks)
                kfa[ks] = *(const bf16x8*)&Ks[cur][ks*4 + (l>>4)][sj*16 + (l & 15)][0];
            #pragma unroll
            for (int qt = 0; qt < 2; ++qt) {
                f32x4 d = (f32x4){0.f, 0.f, 0.f, 0.f};
                #pragma unroll
                for (int ks = 0; ks < 2; ++ks)
                    d = __builtin_amdgcn_mfma_f32_16x16x32_bf16(
                        kfa[ks], qf[qt][ks], d, 0, 0, 0);
                int row = wq + qt*16 + (l & 15);
                int c16 = sj*2 + ((l >> 4) >> 1);
                int sub = (l >> 4) & 1;
                uint2 pv2;
                pv2.x = pk2(__expf(d[0]*0.125f), __expf(d[1]*0.125f));
                pv2.y = pk2(__expf(d[2]*0.125f), __expf(d[3]*0.125f));
                *(uint2*)((char*)Es + row*128 + ((c16 ^ (row & 7))*16 + sub*8)) = pv2;
            }
        }
        bf16x8 efa[2][2];
        #pragma unroll
        for (int qt = 0; qt < 2; ++qt) {
            int row = wq + qt*16 + (l & 15);
            #pragma unroll
            for (int ks = 0; ks < 2; ++ks)
                efa[qt][ks] = *(const bf16x8*)((char*)Es + row*128
                    + (((ks*4 + (l >> 4)) ^ (row & 7))*16));
        }
        #pragma unroll
        for (int j = 0; j < 4; ++j)
            #pragma unroll
            for (int ks = 0; ks < 2; ++ks) {
                bf16x8 vf = *(const bf16x8*)&Vs[cur][ks*4 + (l>>4)][j*16 + (l & 15)][0];
                #pragma unroll
                for (int qt = 0; qt < 2; ++qt)
                    oacc[qt][j] = __builtin_amdgcn_mfma_f32_16x16x32_bf16(
                        efa[qt][ks], vf, oacc[qt][j], 0, 0, 0);
            }
        __syncthreads();
        cur ^= 1;
    }

    #pragma unroll
    for (int qt = 0; qt < 2; ++qt)
        #pragma unroll
        for (int j = 0; j < 4; ++j)
            #pragma unroll
            for (int r = 0; r < 4; ++r) {
                int qq = q0 + wq + qt*16 + (l>>4)*4 + r;
                int dv = j*16 + (l & 15);
                attn_o[(size_t)(b*T_ + qq) * 1024 + h*64 + dv] = f2bf(oacc[qt][j][r]);
            }
}

// ---------------------------------------------------------------------------
// fused norm: y = sum_{z<Z} parts[z] (bf16) (+bias f32) + residb (bf16),
// mean/std norm (Bessel) -> optional outf (f32) / outb (bf16).
// ---------------------------------------------------------------------------
__device__ __forceinline__ float block_reduce_sum_256(float v, float* tmp)
{
    #pragma unroll
    for (int off = 32; off; off >>= 1) v += __shfl_down(v, off, 64);
    int lane = threadIdx.x & 63, w = threadIdx.x >> 6;
    __syncthreads();
    if (lane == 0) tmp[w] = v;
    __syncthreads();
    return tmp[0] + tmp[1] + tmp[2] + tmp[3];
}

template<int Z>
__global__ __launch_bounds__(256) void normZ_fused_kernel(
    const ushort* __restrict__ parts, long zoff,
    const float* __restrict__ bias, const ushort* __restrict__ residb,
    float* __restrict__ outf, ushort* __restrict__ outb)
{
    __shared__ float tmp[4];
    int row = blockIdx.x;
    int tid = threadIdx.x;
    int c0 = tid * 4;
    size_t idx = (size_t)row * D_ + c0;
    float vals[4] = {0.f, 0.f, 0.f, 0.f};
    #pragma unroll
    for (int z = 0; z < Z; ++z) {
        ushort4 p = *(const ushort4*)&parts[idx + (size_t)z * zoff];
        vals[0] += bf2f(p.x); vals[1] += bf2f(p.y);
        vals[2] += bf2f(p.z); vals[3] += bf2f(p.w);
    }
    ushort4 rb = *(const ushort4*)&residb[idx];
    vals[0] += bf2f(rb.x); vals[1] += bf2f(rb.y);
    vals[2] += bf2f(rb.z); vals[3] += bf2f(rb.w);
    if (bias) {
        float4 bv = *(const float4*)&bias[c0];
        vals[0] += bv.x; vals[1] += bv.y; vals[2] += bv.z; vals[3] += bv.w;
    }
    float s = vals[0] + vals[1] + vals[2] + vals[3];
    s = block_reduce_sum_256(s, tmp);
    float m = s * (1.0f / (float)D_);
    float sq = 0.f;
    #pragma unroll
    for (int i = 0; i < 4; ++i) { float c = vals[i] - m; sq += c * c; }
    sq = block_reduce_sum_256(sq, tmp);
    float rs = rsqrtf(sq * (1.0f / (float)(D_ - 1)));
    float4 o;
    o.x = (vals[0] - m) * rs; o.y = (vals[1] - m) * rs;
    o.z = (vals[2] - m) * rs; o.w = (vals[3] - m) * rs;
    if (outf) *(float4*)&outf[idx] = o;
    if (outb) {
        ushort4 ob;
        ob.x = f2bf(o.x); ob.y = f2bf(o.y); ob.z = f2bf(o.z); ob.w = f2bf(o.w);
        *(ushort4*)&outb[idx] = ob;
    }
}

// ---------------------------------------------------------------------------
extern "C" void kernel_launch(void* const* d_in, const int* in_sizes, int n_in,
                              void* d_out, int out_size, void* d_ws, size_t ws_size,
                              hipStream_t stream)
{
    const float* x  = (const float*)d_in[0];
    const float* Wq = (const float*)d_in[1];
    const float* Wk = (const float*)d_in[2];
    const float* Wv = (const float*)d_in[3];
    const float* Wo = (const float*)d_in[4];
    const float* W1 = (const float*)d_in[5];
    const float* b1 = (const float*)d_in[6];
    const float* W2 = (const float*)d_in[7];
    const float* b2 = (const float*)d_in[8];
    float* out = (float*)d_out;

    const size_t MB = (size_t)1 << 20;
    char* base = (char*)d_ws;
    ushort* qkv    = (ushort*)(base +   0*MB);  // 24MB  [QKV..PV]
    ushort* hid    = (ushort*)(base +   0*MB);  // 32MB  [W1..W2]
    ushort* xb     = (ushort*)(base +  24*MB);  //  8MB  [prep..norm1]
    ushort* W2t    = (ushort*)(base +  32*MB);  //  8MB  [prep..W2]
    ushort* Wqkvt  = (ushort*)(base +  40*MB);  //  6MB  [prep..QKV]
    ushort* wpart  = (ushort*)(base +  40*MB);  // 32MB  [W2..norm2]
    ushort* vt     = (ushort*)(base +  46*MB);  //  8MB  [csumv..PV]
    ushort* Wot    = (ushort*)(base +  55*MB);  //  2MB  [prep..Wo]
    ushort* W1t    = (ushort*)(base +  57*MB);  //  8MB  [prep..W1]
    ushort* attn_o = (ushort*)(base +  65*MB);  //  8MB  [PV..Wo]
    ushort* wopart = (ushort*)(base +  73*MB);  // 16MB  [Wo..norm1]
    ushort* out1b  = (ushort*)(base +  89*MB);  //  8MB  [norm1..norm2]

    // 1. single fused prep: all converts + transposes
    prep_kernel<<<dim3(14336), 256, 0, stream>>>(
        x, Wq, Wk, Wv, Wo, W1, W2, xb, Wqkvt, Wot, W1t, W2t);

    // 2. QKV: wide tile, 384 blocks.
    gemm_ntw_kernel<1><<<dim3(3072/256, 4096/128, 1), 256, 0, stream>>>(
        xb, 1024, Wqkvt, 1024, qkv, 3072, 1024, nullptr, nullptr, 0, 0, 0, 0);
    // 3. colsum + V-scale/transpose fused
    csumv_kernel<<<dim3(T_/128, B_*H_), 256, 0, stream>>>(qkv, vt);
    // 4. PV
    attn_pv_kernel<<<dim3(T_/128, B_*H_), 256, 0, stream>>>(qkv, vt, attn_o);
    // 5. Wo split-K2 -> bf16 partials. 512 blocks.
    gemm_nt_kernel<1><<<dim3(1024/128, 4096/128, 2), 256, 0, stream>>>(
        attn_o, 1024, Wot, 1024, wopart, 1024, 512, nullptr, nullptr, 0,
        512, 512, (long)4096*1024);
    // 6. norm1 fused: 2 partials + xb (bf16 resid) -> out1b only
    normZ_fused_kernel<2><<<dim3(BT_), 256, 0, stream>>>(
        wopart, (long)4096*1024, nullptr, xb, nullptr, out1b);
    // 7. FFN up + ReLU: wide tile, 512 blocks.
    gemm_ntw_kernel<1><<<dim3(4096/256, 4096/128, 1), 256, 0, stream>>>(
        out1b, 1024, W1t, 1024, hid, 4096, 1024, b1, nullptr, 1, 0, 0, 0);
    // 8. FFN down: wide tile + split-K4. 512 blocks.
    gemm_ntw_kernel<1><<<dim3(1024/256, 4096/128, 4), 256, 0, stream>>>(
        hid, 4096, W2t, 4096, wpart, 1024, 1024, nullptr, nullptr, 0,
        1024, 1024, (long)4096*1024);
    // 9. norm2 fused: 4 partials + b2 + out1b (bf16 resid) -> out (f32)
    normZ_fused_kernel<4><<<dim3(BT_), 256, 0, stream>>>(
        wpart, (long)4096*1024, b2, out1b, out, nullptr);
}

// Round 19
// 350.979 us; speedup vs baseline: 1.0481x; 1.0105x over previous
//
#include <hip/hip_runtime.h>
#include <hip/hip_bf16.h>
#include <math.h>

#define B_  2
#define T_  2048
#define D_  1024
#define H_  16
#define DK_ 64
#define FF_ 4096
#define BT_ (B_*T_)

typedef __attribute__((ext_vector_type(8))) short bf16x8;
typedef __attribute__((ext_vector_type(4))) float f32x4;

__device__ __forceinline__ ushort f2bf(float f) {
    __hip_bfloat16 h = __float2bfloat16(f);
    return *reinterpret_cast<ushort*>(&h);
}
__device__ __forceinline__ float bf2f(ushort u) {
    __hip_bfloat16 h;
    *reinterpret_cast<ushort*>(&h) = u;
    return __bfloat162float(h);
}
__device__ __forceinline__ uint pk2(float a, float b) {
    return (uint)f2bf(a) | ((uint)f2bf(b) << 16);
}

// async global->LDS, 16B per lane. LDS dest must be wave-uniform base + lane*16.
__device__ __forceinline__ void g2l16(const ushort* g, ushort* l) {
    __builtin_amdgcn_global_load_lds(
        (const __attribute__((address_space(1))) void*)g,
        (__attribute__((address_space(3))) void*)l, 16, 0, 0);
}

// 2D-rect XCD swizzle (neutral but not harmful).
__device__ __forceinline__ void xcd_rect(int gx, int gy, int* bx, int* by) {
    int orig = blockIdx.y * gx + blockIdx.x;
    int xg = (gx & 1) ? 1 : 2;
    int rw = gx / xg, rh = (gy * xg) >> 3;
    int xcd = orig & 7, i = orig >> 3;
    *bx = (xcd % xg) * rw + i % rw;
    *by = (xcd / xg) * rh + i / rw;
}

// ---------------------------------------------------------------------------
// prep: ONE kernel for all input conversions/transposes.
// ---------------------------------------------------------------------------
__global__ __launch_bounds__(256) void prep_kernel(
    const float* __restrict__ x,
    const float* __restrict__ Wq, const float* __restrict__ Wk,
    const float* __restrict__ Wv, const float* __restrict__ Wo,
    const float* __restrict__ W1, const float* __restrict__ W2,
    ushort* __restrict__ xb, ushort* __restrict__ Wqkvt,
    ushort* __restrict__ Wot, ushort* __restrict__ W1t,
    ushort* __restrict__ W2t)
{
    int idx = blockIdx.x;
    int tid = threadIdx.x;
    if (idx >= 12288) {                       // x convert, 2048/block
        int i = (idx - 12288) * 2048 + tid * 4;
        #pragma unroll
        for (int p = 0; p < 2; ++p) {
            float4 v = *(const float4*)(x + i + p * 1024);
            ushort4 o;
            o.x = f2bf(v.x); o.y = f2bf(v.y); o.z = f2bf(v.z); o.w = f2bf(v.w);
            *(ushort4*)(xb + i + p * 1024) = o;
        }
        return;
    }
    __shared__ float t[32][33];
    const float* ib; ushort* ob; int K, N, n0, k0;
    if (idx < 1024) {                         // Wo
        ib = Wo; ob = Wot; K = 1024; N = 1024;
        n0 = (idx & 31) * 32; k0 = (idx >> 5) * 32;
    } else if (idx < 5120) {                  // W1
        int i2 = idx - 1024; ib = W1; ob = W1t; K = 1024; N = 4096;
        n0 = (i2 & 127) * 32; k0 = (i2 >> 7) * 32;
    } else if (idx < 9216) {                  // W2
        int i2 = idx - 5120; ib = W2; ob = W2t; K = 4096; N = 1024;
        n0 = (i2 & 31) * 32; k0 = (i2 >> 5) * 32;
    } else {                                  // Wq/Wk/Wv heads
        int i2 = idx - 9216; int z = i2 >> 6; int t2 = i2 & 63;
        int mat = z >> 4, zz = z & 15;
        ib = (mat == 0 ? Wq : (mat == 1 ? Wk : Wv)) + (size_t)zz * 65536;
        ob = Wqkvt + (size_t)mat * 1048576 + (size_t)zz * 65536;
        K = 1024; N = 64;
        n0 = (t2 & 1) * 32; k0 = (t2 >> 1) * 32;
    }
    int r = tid >> 3, c4 = (tid & 7) * 4;
    float4 v = *(const float4*)(ib + (size_t)(k0 + r) * N + n0 + c4);
    t[r][c4] = v.x; t[r][c4+1] = v.y; t[r][c4+2] = v.z; t[r][c4+3] = v.w;
    __syncthreads();
    int n = tid >> 3, kc = (tid & 7) * 4;
    ushort4 o;
    o.x = f2bf(t[kc+0][n]); o.y = f2bf(t[kc+1][n]);
    o.z = f2bf(t[kc+2][n]); o.w = f2bf(t[kc+3][n]);
    *(ushort4*)(ob + (size_t)(n0 + n) * K + k0 + kc) = o;
}

// ---------------------------------------------------------------------------
// WIDE 128(M)x256(N) NT GEMM, bf16 MFMA, BK=32, 2-phase dbuf, 48KB LDS.
// ---------------------------------------------------------------------------
template<int OUT_BF16>
__global__ __launch_bounds__(256, 2) void gemm_ntw_kernel(
    const ushort* __restrict__ A, int lda,
    const ushort* __restrict__ Bt, int ldb,
    void* __restrict__ C, int ldc, int K,
    const float* __restrict__ bias,
    const float* __restrict__ resid, int relu,
    long aZoff, long bZoff, long cZoff)
{
    __shared__ __attribute__((aligned(16))) ushort As[2][4][128][8];
    __shared__ __attribute__((aligned(16))) ushort Bs[2][4][256][8];

    A  += (size_t)blockIdx.z * aZoff;
    Bt += (size_t)blockIdx.z * bZoff;
    char* Cb = (char*)C + (size_t)blockIdx.z * cZoff * (OUT_BF16 ? 2 : 4);

    int bx, by;
    xcd_rect(gridDim.x, gridDim.y, &bx, &by);

    int row0 = by * 128, col0 = bx * 256;
    int tid = threadIdx.x;
    int w = tid >> 6, l = tid & 63;
    int wr = (w >> 1) * 64, wc = (w & 1) * 128;

    int m0 = tid & 127, kc0 = tid >> 7;
    const ushort* gA = A  + (size_t)(row0 + m0) * lda + kc0 * 8;
    const ushort* gB = Bt + (size_t)(col0 + tid) * ldb;

    f32x4 acc[4][8];
    #pragma unroll
    for (int i = 0; i < 4; ++i)
        #pragma unroll
        for (int j = 0; j < 8; ++j) acc[i][j] = (f32x4){0.f, 0.f, 0.f, 0.f};

    const int NT = K >> 5;
    g2l16(gA,      &As[0][kc0    ][m0][0]);
    g2l16(gA + 16, &As[0][kc0 + 2][m0][0]);
    #pragma unroll
    for (int p = 0; p < 4; ++p)
        g2l16(gB + p*8, &Bs[0][p][tid][0]);
    __syncthreads();

    int cur = 0;
    for (int t = 0; t < NT; ++t) {
        if (t + 1 < NT) {
            int k0 = (t + 1) << 5;
            g2l16(gA + k0,      &As[cur ^ 1][kc0    ][m0][0]);
            g2l16(gA + k0 + 16, &As[cur ^ 1][kc0 + 2][m0][0]);
            #pragma unroll
            for (int p = 0; p < 4; ++p)
                g2l16(gB + k0 + p*8, &Bs[cur ^ 1][p][tid][0]);
        }
        int kc = l >> 4;
        bf16x8 bfr[8];
        #pragma unroll
        for (int j = 0; j < 8; ++j)
            bfr[j] = *(const bf16x8*)&Bs[cur][kc][wc + j*16 + (l & 15)][0];
        #pragma unroll
        for (int i = 0; i < 4; ++i) {
            bf16x8 a = *(const bf16x8*)&As[cur][kc][wr + i*16 + (l & 15)][0];
            #pragma unroll
            for (int j = 0; j < 8; ++j)
                acc[i][j] = __builtin_amdgcn_mfma_f32_16x16x32_bf16(
                    a, bfr[j], acc[i][j], 0, 0, 0);
        }
        __syncthreads();
        cur ^= 1;
    }

    #pragma unroll
    for (int i = 0; i < 4; ++i) {
        int rbase = row0 + wr + i*16 + (l >> 4) * 4;
        #pragma unroll
        for (int j = 0; j < 8; ++j) {
            int col = col0 + wc + j*16 + (l & 15);
            float bv = bias ? bias[col] : 0.f;
            #pragma unroll
            for (int r = 0; r < 4; ++r) {
                int row = rbase + r;
                float val = acc[i][j][r] + bv;
                if (resid) val += resid[(size_t)row * ldc + col];
                if (relu)  val = fmaxf(val, 0.f);
                if (OUT_BF16) ((ushort*)Cb)[(size_t)row * ldc + col] = f2bf(val);
                else          ((float*)Cb)[(size_t)row * ldc + col]  = val;
            }
        }
    }
}

// ---------------------------------------------------------------------------
// 128x128 NT GEMM, BK=32, 2-phase dbuf, 32KB LDS (kept for Wo).
// ---------------------------------------------------------------------------
template<int OUT_BF16>
__global__ __launch_bounds__(256) void gemm_nt_kernel(
    const ushort* __restrict__ A, int lda,
    const ushort* __restrict__ Bt, int ldb,
    void* __restrict__ C, int ldc, int K,
    const float* __restrict__ bias,
    const float* __restrict__ resid, int relu,
    long aZoff, long bZoff, long cZoff)
{
    __shared__ __attribute__((aligned(16))) ushort As[2][4][128][8];
    __shared__ __attribute__((aligned(16))) ushort Bs[2][4][128][8];

    A  += (size_t)blockIdx.z * aZoff;
    Bt += (size_t)blockIdx.z * bZoff;
    char* Cb = (char*)C + (size_t)blockIdx.z * cZoff * (OUT_BF16 ? 2 : 4);

    int bx, by;
    xcd_rect(gridDim.x, gridDim.y, &bx, &by);

    int row0 = by * 128, col0 = bx * 128;
    int tid = threadIdx.x;
    int w = tid >> 6, l = tid & 63;
    int wr = (w >> 1) * 64, wc = (w & 1) * 64;

    int m0 = tid & 127, kc0 = tid >> 7;
    const ushort* ga0 = A  + (size_t)(row0 + m0) * lda + kc0 * 8;
    const ushort* gb0 = Bt + (size_t)(col0 + m0) * ldb + kc0 * 8;

    f32x4 acc[4][4];
    #pragma unroll
    for (int i = 0; i < 4; ++i)
        #pragma unroll
        for (int j = 0; j < 4; ++j) acc[i][j] = (f32x4){0.f, 0.f, 0.f, 0.f};

    const int NT = K >> 5;
    g2l16(ga0,      &As[0][kc0    ][m0][0]);
    g2l16(ga0 + 16, &As[0][kc0 + 2][m0][0]);
    g2l16(gb0,      &Bs[0][kc0    ][m0][0]);
    g2l16(gb0 + 16, &Bs[0][kc0 + 2][m0][0]);
    __syncthreads();

    int cur = 0;
    for (int t = 0; t < NT; ++t) {
        if (t + 1 < NT) {
            int k0 = (t + 1) << 5;
            g2l16(ga0 + k0,      &As[cur ^ 1][kc0    ][m0][0]);
            g2l16(ga0 + k0 + 16, &As[cur ^ 1][kc0 + 2][m0][0]);
            g2l16(gb0 + k0,      &Bs[cur ^ 1][kc0    ][m0][0]);
            g2l16(gb0 + k0 + 16, &Bs[cur ^ 1][kc0 + 2][m0][0]);
        }
        int kc = l >> 4;
        bf16x8 af[4], bfr[4];
        #pragma unroll
        for (int i = 0; i < 4; ++i)
            af[i] = *(const bf16x8*)&As[cur][kc][wr + i*16 + (l & 15)][0];
        #pragma unroll
        for (int j = 0; j < 4; ++j)
            bfr[j] = *(const bf16x8*)&Bs[cur][kc][wc + j*16 + (l & 15)][0];
        #pragma unroll
        for (int i = 0; i < 4; ++i)
            #pragma unroll
            for (int j = 0; j < 4; ++j)
                acc[i][j] = __builtin_amdgcn_mfma_f32_16x16x32_bf16(
                    af[i], bfr[j], acc[i][j], 0, 0, 0);
        __syncthreads();
        cur ^= 1;
    }

    #pragma unroll
    for (int i = 0; i < 4; ++i) {
        int rbase = row0 + wr + i*16 + (l >> 4) * 4;
        #pragma unroll
        for (int j = 0; j < 4; ++j) {
            int col = col0 + wc + j*16 + (l & 15);
            float bv = bias ? bias[col] : 0.f;
            #pragma unroll
            for (int r = 0; r < 4; ++r) {
                int row = rbase + r;
                float val = acc[i][j][r] + bv;
                if (resid) val += resid[(size_t)row * ldc + col];
                if (relu)  val = fmaxf(val, 0.f);
                if (OUT_BF16) ((ushort*)Cb)[(size_t)row * ldc + col] = f2bf(val);
                else          ((float*)Cb)[(size_t)row * ldc + col]  = val;
            }
        }
    }
}

// ---------------------------------------------------------------------------
// csum + vscale fused, Q-tile dbuf, bh-major XCD swizzle, hoisted K-frags,
// T5 setprio around the MFMA+exp cluster.
// ---------------------------------------------------------------------------
__global__ __launch_bounds__(256) void csumv_kernel(
    const ushort* __restrict__ qkv, ushort* __restrict__ vt)
{
    int nwg  = gridDim.x * gridDim.y;
    int orig = blockIdx.y * gridDim.x + blockIdx.x;
    int work = (orig & 7) * (nwg >> 3) + (orig >> 3);
    int bx = work % gridDim.x;
    int bh = work / gridDim.x;
    int b = bh >> 4, h = bh & 15;
    int s0 = bx * 128;
    const ushort* qb = qkv + (size_t)b * T_ * 3072 + h * 64;
    const ushort* kb = qb + 1024;
    const ushort* vb = qb + 2048;
    __shared__ __attribute__((aligned(16))) ushort Ks[8][128][8];
    __shared__ __attribute__((aligned(16))) ushort Qs[2][8][64][8];
    __shared__ float csl[128];
    __shared__ float t[64][65];
    int tid = threadIdx.x, w = tid >> 6, l = tid & 63;
    int scol = w * 32;
    int qq0 = l, kcA = w, kcB = w + 4;

    #pragma unroll
    for (int p = 0; p < 4; ++p) {
        int idx = tid + p * 256;
        int s = idx & 127, kc = idx >> 7;
        *(uint4*)&Ks[kc][s][0] =
            *(const uint4*)(kb + (size_t)(s0 + s) * 3072 + kc * 8);
    }
    g2l16(qb + (size_t)qq0 * 3072 + kcA * 8, &Qs[0][kcA][qq0][0]);
    g2l16(qb + (size_t)qq0 * 3072 + kcB * 8, &Qs[0][kcB][qq0][0]);
    __syncthreads();

    bf16x8 bfr[2][2];
    #pragma unroll
    for (int sj = 0; sj < 2; ++sj)
        #pragma unroll
        for (int ks = 0; ks < 2; ++ks)
            bfr[sj][ks] = *(const bf16x8*)&Ks[ks*4 + (l>>4)][scol + sj*16 + (l & 15)][0];

    float cs[2] = {0.f, 0.f};
    int cur = 0;
    for (int qt = 0; qt < T_ / 64; ++qt) {
        if (qt + 1 < T_ / 64) {
            const ushort* qn = qb + (size_t)((qt + 1) * 64 + qq0) * 3072;
            g2l16(qn + kcA * 8, &Qs[cur ^ 1][kcA][qq0][0]);
            g2l16(qn + kcB * 8, &Qs[cur ^ 1][kcB][qq0][0]);
        }
        bf16x8 af[4][2];
        #pragma unroll
        for (int qi = 0; qi < 4; ++qi)
            #pragma unroll
            for (int ks = 0; ks < 2; ++ks)
                af[qi][ks] = *(const bf16x8*)&Qs[cur][ks*4 + (l>>4)][qi*16 + (l & 15)][0];
        __builtin_amdgcn_s_setprio(1);
        #pragma unroll
        for (int qi = 0; qi < 4; ++qi)
            #pragma unroll
            for (int sj = 0; sj < 2; ++sj) {
                f32x4 d = (f32x4){0.f, 0.f, 0.f, 0.f};
                #pragma unroll
                for (int ks = 0; ks < 2; ++ks)
                    d = __builtin_amdgcn_mfma_f32_16x16x32_bf16(
                        af[qi][ks], bfr[sj][ks], d, 0, 0, 0);
                cs[sj] += __expf(d[0]*0.125f) + __expf(d[1]*0.125f)
                        + __expf(d[2]*0.125f) + __expf(d[3]*0.125f);
            }
        __builtin_amdgcn_s_setprio(0);
        __syncthreads();
        cur ^= 1;
    }
    #pragma unroll
    for (int sj = 0; sj < 2; ++sj) {
        float v = cs[sj];
        v += __shfl_down(v, 32, 64);
        v += __shfl_down(v, 16, 64);
        if (l < 16) csl[scol + sj*16 + l] = v;
    }
    __syncthreads();

    #pragma unroll
    for (int p2 = 0; p2 < 2; ++p2) {
        int sb = s0 + p2 * 64;
        #pragma unroll
        for (int p = 0; p < 2; ++p) {
            int idx = tid + p * 256;
            int s = idx >> 3, c0 = (idx & 7) * 8;
            uint4 raw = *(const uint4*)(vb + (size_t)(sb + s) * 3072 + c0);
            float rc = 1.0f / csl[p2 * 64 + s];
            ushort* u = (ushort*)&raw;
            #pragma unroll
            for (int i = 0; i < 8; ++i) t[s][c0 + i] = bf2f(u[i]) * rc;
        }
        __syncthreads();
        #pragma unroll
        for (int p = 0; p < 2; ++p) {
            int idx = tid + p * 256;
            int dv = idx >> 3, sc = (idx & 7) * 8;
            ushort o[8];
            #pragma unroll
            for (int i = 0; i < 8; ++i) o[i] = f2bf(t[sc + i][dv]);
            *(uint4*)(vt + ((size_t)bh * 64 + dv) * T_ + sb + sc) = *(uint4*)o;
        }
        __syncthreads();
    }
}

// ---------------------------------------------------------------------------
// PV: QBLK=128, K/V dbuf, Q in regs, bh-major XCD swizzle, swapped-QK^T
// packed-E. T5 setprio around both MFMA clusters.
// ---------------------------------------------------------------------------
__global__ __launch_bounds__(256) void attn_pv_kernel(
    const ushort* __restrict__ qkv, const ushort* __restrict__ vt,
    ushort* __restrict__ attn_o)
{
    int nwg  = gridDim.x * gridDim.y;
    int orig = blockIdx.y * gridDim.x + blockIdx.x;
    int work = (orig & 7) * (nwg >> 3) + (orig >> 3);
    int bx = work % gridDim.x;
    int bh = work / gridDim.x;
    int b = bh >> 4, h = bh & 15;
    int q0 = bx * 128;
    const ushort* qb = qkv + (size_t)b * T_ * 3072 + h * 64;
    const ushort* kb = qb + 1024;
    const ushort* vtb = vt + (size_t)bh * 64 * T_;
    __shared__ __attribute__((aligned(16))) ushort Ks[2][8][64][8];
    __shared__ __attribute__((aligned(16))) ushort Vs[2][8][64][8];
    __shared__ __attribute__((aligned(16))) ushort Es[128][64]; // [q][s], swizzled
    int tid = threadIdx.x, w = tid >> 6, l = tid & 63;
    int wq = w * 32;
    int kcA = w, kcB = w + 4;

    bf16x8 qf[2][2];
    #pragma unroll
    for (int qt = 0; qt < 2; ++qt)
        #pragma unroll
        for (int ks = 0; ks < 2; ++ks)
            qf[qt][ks] = *(const bf16x8*)(qb
                + (size_t)(q0 + wq + qt*16 + (l & 15)) * 3072
                + (ks*4 + (l >> 4)) * 8);

    f32x4 oacc[2][4];
    #pragma unroll
    for (int qt = 0; qt < 2; ++qt)
        #pragma unroll
        for (int j = 0; j < 4; ++j) oacc[qt][j] = (f32x4){0.f, 0.f, 0.f, 0.f};

    const int NT = T_ / 64;
    g2l16(kb + (size_t)l * 3072 + kcA * 8, &Ks[0][kcA][l][0]);
    g2l16(kb + (size_t)l * 3072 + kcB * 8, &Ks[0][kcB][l][0]);
    g2l16(vtb + (size_t)l * T_ + kcA * 8,  &Vs[0][kcA][l][0]);
    g2l16(vtb + (size_t)l * T_ + kcB * 8,  &Vs[0][kcB][l][0]);
    __syncthreads();

    int cur = 0;
    for (int st = 0; st < NT; ++st) {
        if (st + 1 < NT) {
            int s1 = (st + 1) * 64;
            g2l16(kb + (size_t)(s1 + l) * 3072 + kcA * 8, &Ks[cur^1][kcA][l][0]);
            g2l16(kb + (size_t)(s1 + l) * 3072 + kcB * 8, &Ks[cur^1][kcB][l][0]);
            g2l16(vtb + (size_t)l * T_ + s1 + kcA * 8,    &Vs[cur^1][kcA][l][0]);
            g2l16(vtb + (size_t)l * T_ + s1 + kcB * 8,    &Vs[cur^1][kcB][l][0]);
        }
        __builtin_amdgcn_s_setprio(1);
        #pragma unroll
        for (int sj = 0; sj < 4; ++sj) {
            bf16x8 kfa[2];
            #pragma unroll
            for (int ks = 0; ks < 2; ++ks)
                kfa[ks] = *(const bf16x8*)&Ks[cur][ks*4 + (l>>4)][sj*16 + (l & 15)][0];
            #pragma unroll
            for (int qt = 0; qt < 2; ++qt) {
                f32x4 d = (f32x4){0.f, 0.f, 0.f, 0.f};
                #pragma unroll
                for (int ks = 0; ks < 2; ++ks)
                    d = __builtin_amdgcn_mfma_f32_16x16x32_bf16(
                        kfa[ks], qf[qt][ks], d, 0, 0, 0);
                int row = wq + qt*16 + (l & 15);
                int c16 = sj*2 + ((l >> 4) >> 1);
                int sub = (l >> 4) & 1;
                uint2 pv2;
                pv2.x = pk2(__expf(d[0]*0.125f), __expf(d[1]*0.125f));
                pv2.y = pk2(__expf(d[2]*0.125f), __expf(d[3]*0.125f));
                *(uint2*)((char*)Es + row*128 + ((c16 ^ (row & 7))*16 + sub*8)) = pv2;
            }
        }
        __builtin_amdgcn_s_setprio(0);
        bf16x8 efa[2][2];
        #pragma unroll
        for (int qt = 0; qt < 2; ++qt) {
            int row = wq + qt*16 + (l & 15);
            #pragma unroll
            for (int ks = 0; ks < 2; ++ks)
                efa[qt][ks] = *(const bf16x8*)((char*)Es + row*128
                    + (((ks*4 + (l >> 4)) ^ (row & 7))*16));
        }
        __builtin_amdgcn_s_setprio(1);
        #pragma unroll
        for (int j = 0; j < 4; ++j)
            #pragma unroll
            for (int ks = 0; ks < 2; ++ks) {
                bf16x8 vf = *(const bf16x8*)&Vs[cur][ks*4 + (l>>4)][j*16 + (l & 15)][0];
                #pragma unroll
                for (int qt = 0; qt < 2; ++qt)
                    oacc[qt][j] = __builtin_amdgcn_mfma_f32_16x16x32_bf16(
                        efa[qt][ks], vf, oacc[qt][j], 0, 0, 0);
            }
        __builtin_amdgcn_s_setprio(0);
        __syncthreads();
        cur ^= 1;
    }

    #pragma unroll
    for (int qt = 0; qt < 2; ++qt)
        #pragma unroll
        for (int j = 0; j < 4; ++j)
            #pragma unroll
            for (int r = 0; r < 4; ++r) {
                int qq = q0 + wq + qt*16 + (l>>4)*4 + r;
                int dv = j*16 + (l & 15);
                attn_o[(size_t)(b*T_ + qq) * 1024 + h*64 + dv] = f2bf(oacc[qt][j][r]);
            }
}

// ---------------------------------------------------------------------------
// fused norm: y = sum_{z<Z} parts[z] (bf16) (+bias f32) + residb (bf16),
// mean/std norm (Bessel) -> optional outf (f32) / outb (bf16).
// ---------------------------------------------------------------------------
__device__ __forceinline__ float block_reduce_sum_256(float v, float* tmp)
{
    #pragma unroll
    for (int off = 32; off; off >>= 1) v += __shfl_down(v, off, 64);
    int lane = threadIdx.x & 63, w = threadIdx.x >> 6;
    __syncthreads();
    if (lane == 0) tmp[w] = v;
    __syncthreads();
    return tmp[0] + tmp[1] + tmp[2] + tmp[3];
}

template<int Z>
__global__ __launch_bounds__(256) void normZ_fused_kernel(
    const ushort* __restrict__ parts, long zoff,
    const float* __restrict__ bias, const ushort* __restrict__ residb,
    float* __restrict__ outf, ushort* __restrict__ outb)
{
    __shared__ float tmp[4];
    int row = blockIdx.x;
    int tid = threadIdx.x;
    int c0 = tid * 4;
    size_t idx = (size_t)row * D_ + c0;
    float vals[4] = {0.f, 0.f, 0.f, 0.f};
    #pragma unroll
    for (int z = 0; z < Z; ++z) {
        ushort4 p = *(const ushort4*)&parts[idx + (size_t)z * zoff];
        vals[0] += bf2f(p.x); vals[1] += bf2f(p.y);
        vals[2] += bf2f(p.z); vals[3] += bf2f(p.w);
    }
    ushort4 rb = *(const ushort4*)&residb[idx];
    vals[0] += bf2f(rb.x); vals[1] += bf2f(rb.y);
    vals[2] += bf2f(rb.z); vals[3] += bf2f(rb.w);
    if (bias) {
        float4 bv = *(const float4*)&bias[c0];
        vals[0] += bv.x; vals[1] += bv.y; vals[2] += bv.z; vals[3] += bv.w;
    }
    float s = vals[0] + vals[1] + vals[2] + vals[3];
    s = block_reduce_sum_256(s, tmp);
    float m = s * (1.0f / (float)D_);
    float sq = 0.f;
    #pragma unroll
    for (int i = 0; i < 4; ++i) { float c = vals[i] - m; sq += c * c; }
    sq = block_reduce_sum_256(sq, tmp);
    float rs = rsqrtf(sq * (1.0f / (float)(D_ - 1)));
    float4 o;
    o.x = (vals[0] - m) * rs; o.y = (vals[1] - m) * rs;
    o.z = (vals[2] - m) * rs; o.w = (vals[3] - m) * rs;
    if (outf) *(float4*)&outf[idx] = o;
    if (outb) {
        ushort4 ob;
        ob.x = f2bf(o.x); ob.y = f2bf(o.y); ob.z = f2bf(o.z); ob.w = f2bf(o.w);
        *(ushort4*)&outb[idx] = ob;
    }
}

// ---------------------------------------------------------------------------
extern "C" void kernel_launch(void* const* d_in, const int* in_sizes, int n_in,
                              void* d_out, int out_size, void* d_ws, size_t ws_size,
                              hipStream_t stream)
{
    const float* x  = (const float*)d_in[0];
    const float* Wq = (const float*)d_in[1];
    const float* Wk = (const float*)d_in[2];
    const float* Wv = (const float*)d_in[3];
    const float* Wo = (const float*)d_in[4];
    const float* W1 = (const float*)d_in[5];
    const float* b1 = (const float*)d_in[6];
    const float* W2 = (const float*)d_in[7];
    const float* b2 = (const float*)d_in[8];
    float* out = (float*)d_out;

    const size_t MB = (size_t)1 << 20;
    char* base = (char*)d_ws;
    ushort* qkv    = (ushort*)(base +   0*MB);  // 24MB  [QKV..PV]
    ushort* hid    = (ushort*)(base +   0*MB);  // 32MB  [W1..W2]
    ushort* xb     = (ushort*)(base +  24*MB);  //  8MB  [prep..norm1]
    ushort* W2t    = (ushort*)(base +  32*MB);  //  8MB  [prep..W2]
    ushort* Wqkvt  = (ushort*)(base +  40*MB);  //  6MB  [prep..QKV]
    ushort* wpart  = (ushort*)(base +  40*MB);  // 32MB  [W2..norm2]
    ushort* vt     = (ushort*)(base +  46*MB);  //  8MB  [csumv..PV]
    ushort* Wot    = (ushort*)(base +  55*MB);  //  2MB  [prep..Wo]
    ushort* W1t    = (ushort*)(base +  57*MB);  //  8MB  [prep..W1]
    ushort* attn_o = (ushort*)(base +  65*MB);  //  8MB  [PV..Wo]
    ushort* wopart = (ushort*)(base +  73*MB);  // 16MB  [Wo..norm1]
    ushort* out1b  = (ushort*)(base +  89*MB);  //  8MB  [norm1..norm2]

    // 1. single fused prep: all converts + transposes
    prep_kernel<<<dim3(14336), 256, 0, stream>>>(
        x, Wq, Wk, Wv, Wo, W1, W2, xb, Wqkvt, Wot, W1t, W2t);

    // 2. QKV: wide tile, 384 blocks.
    gemm_ntw_kernel<1><<<dim3(3072/256, 4096/128, 1), 256, 0, stream>>>(
        xb, 1024, Wqkvt, 1024, qkv, 3072, 1024, nullptr, nullptr, 0, 0, 0, 0);
    // 3. colsum + V-scale/transpose fused
    csumv_kernel<<<dim3(T_/128, B_*H_), 256, 0, stream>>>(qkv, vt);
    // 4. PV
    attn_pv_kernel<<<dim3(T_/128, B_*H_), 256, 0, stream>>>(qkv, vt, attn_o);
    // 5. Wo split-K2 -> bf16 partials. 512 blocks.
    gemm_nt_kernel<1><<<dim3(1024/128, 4096/128, 2), 256, 0, stream>>>(
        attn_o, 1024, Wot, 1024, wopart, 1024, 512, nullptr, nullptr, 0,
        512, 512, (long)4096*1024);
    // 6. norm1 fused: 2 partials + xb (bf16 resid) -> out1b only
    normZ_fused_kernel<2><<<dim3(BT_), 256, 0, stream>>>(
        wopart, (long)4096*1024, nullptr, xb, nullptr, out1b);
    // 7. FFN up + ReLU: wide tile, 512 blocks.
    gemm_ntw_kernel<1><<<dim3(4096/256, 4096/128, 1), 256, 0, stream>>>(
        out1b, 1024, W1t, 1024, hid, 4096, 1024, b1, nullptr, 1, 0, 0, 0);
    // 8. FFN down: wide tile + split-K4. 512 blocks.
    gemm_ntw_kernel<1><<<dim3(1024/256, 4096/128, 4), 256, 0, stream>>>(
        hid, 4096, W2t, 4096, wpart, 1024, 1024, nullptr, nullptr, 0,
        1024, 1024, (long)4096*1024);
    // 9. norm2 fused: 4 partials + b2 + out1b (bf16 resid) -> out (f32)
    normZ_fused_kernel<4><<<dim3(BT_), 256, 0, stream>>>(
        wpart, (long)4096*1024, b2, out1b, out, nullptr);
}